// Round 6
// baseline (922.319 us; speedup 1.0000x reference)
//
#include <hip/hip_runtime.h>
#include <hip/hip_bf16.h>
#include <math.h>

#define GN 8192
#define GD 128
#define GH 2
#define GK 3
#define NEG_SLOPE 0.2f
#define LN_EPS 1e-5f

using short8  = __attribute__((ext_vector_type(8)))  short;
using float16 = __attribute__((ext_vector_type(16))) float;

__device__ __forceinline__ float wred(float v) {
    #pragma unroll
    for (int o = 32; o > 0; o >>= 1) v += __shfl_xor(v, o, 64);
    return v;
}

__device__ __forceinline__ float rawbf2f(unsigned short s) {
    return __uint_as_float(((unsigned)s) << 16);
}
__device__ __forceinline__ unsigned short f2rawbf(float f) {
    __hip_bfloat16 b = __float2bfloat16(f);
    unsigned short r; __builtin_memcpy(&r, &b, 2);
    return r;
}
__device__ __forceinline__ unsigned umin2(unsigned a, unsigned b) { return a < b ? a : b; }
__device__ __forceinline__ unsigned umax2(unsigned a, unsigned b) { return a > b ? a : b; }

__global__ void k_zero(int* p, int n) {
    int t = blockIdx.x * 256 + threadIdx.x;
    if (t < n) p[t] = 0;
}

// one wave per row: sq[row], xa=[-2x bf16 | hi(sq+512) lo | 0..], xb=[x bf16 | 1 1 | 0..]
__global__ void k_conv(const float* __restrict__ x, float* __restrict__ sq,
                       unsigned short* __restrict__ xa, unsigned short* __restrict__ xb) {
    int row = blockIdx.x * 4 + (threadIdx.x >> 6);
    int lane = threadIdx.x & 63;
    const float* xr = x + (size_t)row * GD;
    float a0 = xr[lane], a1 = xr[lane + 64];
    float s = wred(a0 * a0 + a1 * a1);
    unsigned short* ar = xa + (size_t)row * 144;
    unsigned short* br = xb + (size_t)row * 144;
    ar[lane] = f2rawbf(-2.f * a0); ar[lane + 64] = f2rawbf(-2.f * a1);
    br[lane] = f2rawbf(a0);        br[lane + 64] = f2rawbf(a1);
    if (lane < 16) {
        unsigned short av = 0, bv = 0;
        if (lane == 0)      { av = f2rawbf(s + 512.f); bv = 0x3F80; }
        else if (lane == 1) { float hi = rawbf2f(f2rawbf(s + 512.f));
                              av = f2rawbf(s + 512.f - hi); bv = 0x3F80; }
        ar[128 + lane] = av; br[128 + lane] = bv;
        if (lane == 0) sq[row] = s;
    }
}

// fused xp = x@W and attention dots a_s,a_d; 16 nodes per block, col t per thread.
__global__ void k_attn(const float* __restrict__ x,
                       const float* __restrict__ W,
                       const float* __restrict__ att_src,
                       const float* __restrict__ att_dst,
                       float* __restrict__ a_s, float* __restrict__ a_d) {
    __shared__ float xs[16][GD];
    __shared__ float xpls[16][256];
    int t = threadIdx.x;
    int i0 = blockIdx.x * 16;
    #pragma unroll
    for (int s = 0; s < 2; s++) {
        int f = t + 256 * s;
        int r = f >> 5, c4 = (f & 31) << 2;
        *(float4*)&xs[r][c4] = *(const float4*)(x + (size_t)(i0 + r) * GD + c4);
    }
    __syncthreads();
    float acc[16];
    #pragma unroll
    for (int r = 0; r < 16; r++) acc[r] = 0.f;
    for (int d = 0; d < GD; d++) {
        float wv = W[d * 256 + t];
        #pragma unroll
        for (int r = 0; r < 16; r++) acc[r] += xs[r][d] * wv;
    }
    #pragma unroll
    for (int r = 0; r < 16; r++) xpls[r][t] = acc[r];
    __syncthreads();
    int wid = t >> 6, lane = t & 63;
    for (int jj = 0; jj < 8; jj++) {
        int job = wid * 8 + jj;
        int r = job >> 1, h = job & 1;
        float v0 = xpls[r][h * 128 + lane];
        float v1 = xpls[r][h * 128 + 64 + lane];
        float s = v0 * att_src[h * GD + lane] + v1 * att_src[h * GD + lane + 64];
        float d = v0 * att_dst[h * GD + lane] + v1 * att_dst[h * GD + lane + 64];
        s = wred(s); d = wred(d);
        if (lane == 0) { a_s[(i0 + r) * 2 + h] = s; a_d[(i0 + r) * 2 + h] = d; }
    }
}

// sorted top-6 of unsigned keys, branchless bubble insert
struct Top6 {
    unsigned a0, a1, a2, a3, a4, a5;
    __device__ __forceinline__ void init() { a0=a1=a2=a3=a4=a5=0xFFFFFFFFu; }
    __device__ __forceinline__ void insert(unsigned k) {
        unsigned m0 = umax2(a0, k);  a0 = umin2(a0, k);
        unsigned m1 = umax2(a1, m0); a1 = umin2(a1, m0);
        unsigned m2 = umax2(a2, m1); a2 = umin2(a2, m1);
        unsigned m3 = umax2(a3, m2); a3 = umin2(a3, m2);
        unsigned m4 = umax2(a4, m3); a4 = umin2(a4, m3);
        a5 = umin2(a5, m4);
    }
};

// MFMA candidate kNN. score'_ij = 512 + sq_i - 2 x_i.x_j (> 0 -> raw bits monotone).
__launch_bounds__(256, 2)
__global__ void k_gemm_topk(const unsigned short* __restrict__ xa,
                            const unsigned short* __restrict__ xb,
                            unsigned* __restrict__ cand) {
    __shared__ unsigned short At[18 * 128 * 8];
    int t = threadIdx.x;
    int w = t >> 6, lane = t & 63, h = lane >> 5, n = lane & 31;
    int col = blockIdx.x * 128 + w * 32 + n;
    int sb = blockIdx.y;

    short8 bfrag[9];
    #pragma unroll
    for (int kc = 0; kc < 9; kc++)
        bfrag[kc] = *(const short8*)(xb + (size_t)col * 144 + (2 * kc + h) * 8);

    Top6 T; T.init();

    for (int it = 0; it < 8; it++) {
        int rowbase = sb * 1024 + it * 128;
        __syncthreads();
        #pragma unroll
        for (int q = t; q < 18 * 128; q += 256) {
            int kb = q >> 7, r = q & 127;
            *(uint4*)&At[(kb * 128 + r) * 8] =
                *(const uint4*)(xa + (size_t)(rowbase + r) * 144 + kb * 8);
        }
        __syncthreads();

        float16 acc[4];
        #pragma unroll
        for (int rs = 0; rs < 4; rs++) acc[rs] = (float16)(0.f);

        #pragma unroll
        for (int kc = 0; kc < 9; kc++) {
            short8 a[4];
            #pragma unroll
            for (int rs = 0; rs < 4; rs++)
                a[rs] = *(const short8*)&At[((2 * kc + h) * 128 + rs * 32 + n) * 8];
            #pragma unroll
            for (int rs = 0; rs < 4; rs++)
                acc[rs] = __builtin_amdgcn_mfma_f32_32x32x16_bf16(a[rs], bfrag[kc], acc[rs], 0, 0, 0);
        }

        #pragma unroll
        for (int rs = 0; rs < 4; rs++) {
            float16 A = acc[rs];
            int rb = rowbase + 4 * h + rs * 32;
            unsigned kk[16];
            #pragma unroll
            for (int r = 0; r < 16; r++)
                kk[r] = (__float_as_uint(A[r]) & 0xFFFFE000u) |
                        (unsigned)(rb + (r & 3) + 8 * (r >> 2));
            unsigned ma = umin2(umin2(umin2(kk[0],kk[1]),umin2(kk[2],kk[3])),
                                umin2(umin2(kk[4],kk[5]),umin2(kk[6],kk[7])));
            unsigned mb = umin2(umin2(umin2(kk[8],kk[9]),umin2(kk[10],kk[11])),
                                umin2(umin2(kk[12],kk[13]),umin2(kk[14],kk[15])));
            if (umin2(ma, mb) <= T.a5) {
                #pragma unroll
                for (int r = 0; r < 16; r++) T.insert(kk[r]);
            }
        }
    }

    unsigned p0 = (unsigned)__shfl_xor((int)T.a0, 32), p1 = (unsigned)__shfl_xor((int)T.a1, 32),
             p2 = (unsigned)__shfl_xor((int)T.a2, 32), p3 = (unsigned)__shfl_xor((int)T.a3, 32),
             p4 = (unsigned)__shfl_xor((int)T.a4, 32), p5 = (unsigned)__shfl_xor((int)T.a5, 32);
    T.insert(p0); T.insert(p1); T.insert(p2); T.insert(p3); T.insert(p4); T.insert(p5);

    if (h == 0) {
        unsigned* c0 = cand + (size_t)col * 48 + sb * 6;
        c0[0]=T.a0; c0[1]=T.a1; c0[2]=T.a2; c0[3]=T.a3; c0[4]=T.a4; c0[5]=T.a5;
    }
}

__device__ __forceinline__ int clampN(int v) {
    return v < 0 ? 0 : (v >= GN ? GN - 1 : v);
}

// exact fp32 refine + degree count
__global__ void k_refine(const unsigned* __restrict__ cand,
                         const float* __restrict__ x, const float* __restrict__ sq,
                         int* __restrict__ fidx, int* __restrict__ cnt) {
    __shared__ float xjs[GD];
    __shared__ float dv[48];
    __shared__ int   di[48];
    int j = blockIdx.x, t = threadIdx.x;
    if (t < GD) xjs[t] = x[(size_t)j * GD + t];
    __syncthreads();
    int wv = t >> 6, lane = t & 63;
    for (int c = wv; c < 48; c += 4) {
        int idx = (int)(cand[(size_t)j * 48 + c] & 8191u);
        const float* xi = x + (size_t)idx * GD;
        float p = xjs[lane] * xi[lane] + xjs[lane + 64] * xi[lane + 64];
        p = wred(p);
        if (lane == 0) { dv[c] = sq[j] + sq[idx] - 2.f * p; di[c] = idx; }
    }
    __syncthreads();
    if (t == 0) {
        float v0 = 1e30f, v1 = 1e30f, v2 = 1e30f;
        int   i0 = 0x7fffffff, i1 = 0x7fffffff, i2 = 0x7fffffff;
        for (int c = 0; c < 48; c++) {
            float v = dv[c]; int id = di[c];
            if (v < v2 || (v == v2 && id < i2)) {
                if (v < v1 || (v == v1 && id < i1)) {
                    v2 = v1; i2 = i1;
                    if (v < v0 || (v == v0 && id < i0)) { v1 = v0; i1 = i0; v0 = v; i0 = id; }
                    else                                 { v1 = v; i1 = id; }
                } else { v2 = v; i2 = id; }
            }
        }
        i0 = clampN(i0); i1 = clampN(i1); i2 = clampN(i2);
        fidx[j * 3 + 0] = i0; fidx[j * 3 + 1] = i1; fidx[j * 3 + 2] = i2;
        atomicAdd(&cnt[i0], 1); atomicAdd(&cnt[i1], 1); atomicAdd(&cnt[i2], 1);
    }
}

__global__ void k_scan(const int* __restrict__ cnt, int* __restrict__ offs) {
    __shared__ int part[256];
    int t = threadIdx.x;
    int base = t * 32;
    int loc[32];
    int s = 0;
    #pragma unroll
    for (int k = 0; k < 32; k++) { loc[k] = s; s += cnt[base + k]; }
    part[t] = s;
    __syncthreads();
    if (t == 0) {
        int run = 0;
        for (int k = 0; k < 256; k++) { int v = part[k]; part[k] = run; run += v; }
        offs[GN] = run;
    }
    __syncthreads();
    int b = part[t];
    #pragma unroll
    for (int k = 0; k < 32; k++) offs[base + k] = b + loc[k];
}

__global__ void k_fill(const int* __restrict__ fidx, const int* __restrict__ offs,
                       int* __restrict__ cursor, int* __restrict__ elist) {
    int eid = blockIdx.x * 256 + threadIdx.x;
    int i = clampN(fidx[eid]);
    int pos = atomicAdd(&cursor[i], 1);
    int slot = offs[i] + pos;
    if (slot < GN * GK) elist[slot] = eid / 3;
}

// per-node softmax normalization: aw[k] = exp(e-m) per head; dens = 0.5/denom
__global__ void k_alpha(const int* __restrict__ offs, const int* __restrict__ elst,
                        const float* __restrict__ a_s, const float* __restrict__ a_d,
                        float2* __restrict__ aw, float2* __restrict__ dens) {
    int i = blockIdx.x * 256 + threadIdx.x;
    int s = offs[i], e = offs[i + 1];
    float ad0 = a_d[i * 2], ad1 = a_d[i * 2 + 1];
    float m0 = -1e30f, m1 = -1e30f;
    for (int k = s; k < e; k++) {
        int j = elst[k];
        float2 as = ((const float2*)a_s)[j];
        float e0 = as.x + ad0; e0 = e0 >= 0.f ? e0 : NEG_SLOPE * e0;
        float e1 = as.y + ad1; e1 = e1 >= 0.f ? e1 : NEG_SLOPE * e1;
        m0 = fmaxf(m0, e0); m1 = fmaxf(m1, e1);
    }
    float d0 = 0.f, d1 = 0.f;
    for (int k = s; k < e; k++) {
        int j = elst[k];
        float2 as = ((const float2*)a_s)[j];
        float e0 = as.x + ad0; e0 = e0 >= 0.f ? e0 : NEG_SLOPE * e0;
        float e1 = as.y + ad1; e1 = e1 >= 0.f ? e1 : NEG_SLOPE * e1;
        float w0 = expf(e0 - m0), w1 = expf(e1 - m1);
        d0 += w0; d1 += w1;
        aw[k] = make_float2(w0, w1);
    }
    dens[i] = make_float2(0.5f / d0, 0.5f / d1);
}

// fused: z-accumulate (wave per 4 nodes) -> GEMM y = [z0|z1]@Wcat + bias -> LN/ReLU/residual
__global__ void k_out(const int* __restrict__ offs, const int* __restrict__ elst,
                      const float2* __restrict__ aw, const float2* __restrict__ dens,
                      const float* __restrict__ x, const float* __restrict__ W,
                      const float* __restrict__ bias, const float* __restrict__ gamma,
                      const float* __restrict__ beta, float* __restrict__ out) {
    __shared__ float zs[16][256];   // 16 KB
    __shared__ float os[16][128];   // 8 KB
    int t = threadIdx.x, i0 = blockIdx.x * 16;
    int wv = t >> 6, lane = t & 63;

    // phase A: weighted neighbor sum
    #pragma unroll
    for (int nn = 0; nn < 4; nn++) {
        int r = wv * 4 + nn, node = i0 + r;
        int s = offs[node], e = offs[node + 1];
        float z00 = 0.f, z01 = 0.f, z10 = 0.f, z11 = 0.f;
        for (int k = s; k < e; k++) {
            int j = elst[k];
            float2 al = aw[k];
            float xv0 = x[(size_t)j * GD + lane];
            float xv1 = x[(size_t)j * GD + 64 + lane];
            z00 += al.x * xv0; z01 += al.x * xv1;
            z10 += al.y * xv0; z11 += al.y * xv1;
        }
        float2 dn = dens[node];
        zs[r][lane]       = z00 * dn.x; zs[r][64 + lane]  = z01 * dn.x;
        zs[r][128 + lane] = z10 * dn.y; zs[r][192 + lane] = z11 * dn.y;
    }
    __syncthreads();

    // phase B: y[c] = bias[c] + sum_d z0[d] W[d][c] + z1[d] W[d][128+c]
    int rh = t >> 7, c = t & 127;
    float acc[8];
    float bv = bias[c];
    #pragma unroll
    for (int r = 0; r < 8; r++) acc[r] = bv;
    for (int d4 = 0; d4 < 32; d4++) {
        int d = d4 * 4;
        float4 z0[8], z1[8];
        #pragma unroll
        for (int r = 0; r < 8; r++) {
            z0[r] = *(const float4*)&zs[rh * 8 + r][d];
            z1[r] = *(const float4*)&zs[rh * 8 + r][128 + d];
        }
        #pragma unroll
        for (int q = 0; q < 4; q++) {
            float w0 = W[(d + q) * 256 + c];
            float w1 = W[(d + q) * 256 + 128 + c];
            #pragma unroll
            for (int r = 0; r < 8; r++) {
                float a0 = (q == 0) ? z0[r].x : (q == 1) ? z0[r].y : (q == 2) ? z0[r].z : z0[r].w;
                float a1 = (q == 0) ? z1[r].x : (q == 1) ? z1[r].y : (q == 2) ? z1[r].z : z1[r].w;
                acc[r] += a0 * w0 + a1 * w1;
            }
        }
    }
    #pragma unroll
    for (int r = 0; r < 8; r++) os[rh * 8 + r][c] = acc[r];
    __syncthreads();

    // phase C: LN + ReLU + residual
    #pragma unroll
    for (int nn = 0; nn < 4; nn++) {
        int r = wv * 4 + nn, node = i0 + r;
        float y0 = os[r][lane], y1 = os[r][lane + 64];
        float mu = wred(y0 + y1) * (1.f / 128.f);
        float c0 = y0 - mu, c1 = y1 - mu;
        float var = wred(c0 * c0 + c1 * c1) * (1.f / 128.f);
        float rs2 = 1.f / sqrtf(var + LN_EPS);
        float n0 = c0 * rs2 * gamma[lane] + beta[lane];
        float n1 = c1 * rs2 * gamma[lane + 64] + beta[lane + 64];
        n0 = n0 > 0.f ? n0 : 0.f;
        n1 = n1 > 0.f ? n1 : 0.f;
        out[(size_t)node * GD + lane]      = x[(size_t)node * GD + lane] + n0;
        out[(size_t)node * GD + lane + 64] = x[(size_t)node * GD + lane + 64] + n1;
    }
}

extern "C" void kernel_launch(void* const* d_in, const int* in_sizes, int n_in,
                              void* d_out, int out_size, void* d_ws, size_t ws_size,
                              hipStream_t stream) {
    const float* x       = (const float*)d_in[0];
    const float* W       = (const float*)d_in[2];
    const float* att_src = (const float*)d_in[3];
    const float* att_dst = (const float*)d_in[4];
    const float* bias    = (const float*)d_in[5];
    const float* gamma   = (const float*)d_in[6];
    const float* beta    = (const float*)d_in[7];
    float* out = (float*)d_out;

    char* w = (char*)d_ws;
    unsigned short* xa = (unsigned short*)w; w += (size_t)GN * 144 * 2;
    unsigned short* xb = (unsigned short*)w; w += (size_t)GN * 144 * 2;
    unsigned* cand = (unsigned*)w;           w += (size_t)GN * 48 * 4;
    float* sq   = (float*)w; w += (size_t)GN * 4;
    float* a_s  = (float*)w; w += (size_t)GN * GH * 4;
    float* a_d  = (float*)w; w += (size_t)GN * GH * 4;
    int*   fidx = (int*)w;   w += (size_t)GN * GK * 4;
    int*   cnt  = (int*)w;   w += (size_t)GN * 4;      // cnt|curs contiguous
    int*   curs = (int*)w;   w += (size_t)GN * 4;
    int*   offs = (int*)w;   w += (size_t)(GN + 1) * 4;
    int*   elst = (int*)w;   w += (size_t)GN * GK * 4;
    float2* aw  = (float2*)w; w += (size_t)GN * GK * 8;
    float2* dens = (float2*)w; w += (size_t)GN * 8;
    size_t need = (size_t)((char*)w - (char*)d_ws);
    if (ws_size < need) return;   // diagnostic guard

    k_zero<<<(2 * GN + 255) / 256, 256, 0, stream>>>(cnt, 2 * GN);
    k_conv<<<GN / 4, 256, 0, stream>>>(x, sq, xa, xb);
    k_attn<<<GN / 16, 256, 0, stream>>>(x, W, att_src, att_dst, a_s, a_d);
    k_gemm_topk<<<dim3(64, 8), 256, 0, stream>>>(xa, xb, cand);
    k_refine<<<GN, 256, 0, stream>>>(cand, x, sq, fidx, cnt);
    k_scan<<<1, 256, 0, stream>>>(cnt, offs);
    k_fill<<<GN * GK / 256, 256, 0, stream>>>(fidx, offs, curs, elst);
    k_alpha<<<GN / 256, 256, 0, stream>>>(offs, elst, a_s, a_d, aw, dens);
    k_out<<<GN / 16, 256, 0, stream>>>(offs, elst, aw, dens, x, W, bias, gamma, beta, out);
}

// Round 7
// 329.584 us; speedup vs baseline: 2.7984x; 2.7984x over previous
//
#include <hip/hip_runtime.h>
#include <hip/hip_bf16.h>
#include <math.h>

#define GN 8192
#define GD 128
#define GH 2
#define GK 3
#define NEG_SLOPE 0.2f
#define LN_EPS 1e-5f

using short8  = __attribute__((ext_vector_type(8)))  short;
using float16 = __attribute__((ext_vector_type(16))) float;

__device__ __forceinline__ float wred(float v) {
    #pragma unroll
    for (int o = 32; o > 0; o >>= 1) v += __shfl_xor(v, o, 64);
    return v;
}

__device__ __forceinline__ float rawbf2f(unsigned short s) {
    return __uint_as_float(((unsigned)s) << 16);
}
__device__ __forceinline__ unsigned short f2rawbf(float f) {
    __hip_bfloat16 b = __float2bfloat16(f);
    unsigned short r; __builtin_memcpy(&r, &b, 2);
    return r;
}
__device__ __forceinline__ unsigned umin2(unsigned a, unsigned b) { return a < b ? a : b; }
__device__ __forceinline__ unsigned umax2(unsigned a, unsigned b) { return a > b ? a : b; }

__global__ void k_zero(int* p, int n) {
    int t = blockIdx.x * 256 + threadIdx.x;
    if (t < n) p[t] = 0;
}

// one wave per row: sq[row], xa=[-2x bf16 | hi(sq+512) lo | 0..], xb=[x bf16 | 1 1 | 0..]
__global__ void k_conv(const float* __restrict__ x, float* __restrict__ sq,
                       unsigned short* __restrict__ xa, unsigned short* __restrict__ xb) {
    int row = blockIdx.x * 4 + (threadIdx.x >> 6);
    int lane = threadIdx.x & 63;
    const float* xr = x + (size_t)row * GD;
    float a0 = xr[lane], a1 = xr[lane + 64];
    float s = wred(a0 * a0 + a1 * a1);
    unsigned short* ar = xa + (size_t)row * 144;
    unsigned short* br = xb + (size_t)row * 144;
    ar[lane] = f2rawbf(-2.f * a0); ar[lane + 64] = f2rawbf(-2.f * a1);
    br[lane] = f2rawbf(a0);        br[lane + 64] = f2rawbf(a1);
    if (lane < 16) {
        unsigned short av = 0, bv = 0;
        if (lane == 0)      { av = f2rawbf(s + 512.f); bv = 0x3F80; }
        else if (lane == 1) { float hi = rawbf2f(f2rawbf(s + 512.f));
                              av = f2rawbf(s + 512.f - hi); bv = 0x3F80; }
        ar[128 + lane] = av; br[128 + lane] = bv;
        if (lane == 0) sq[row] = s;
    }
}

// fused xp = x@W and attention dots a_s,a_d; 16 nodes per block, col t per thread.
__global__ void k_attn(const float* __restrict__ x,
                       const float* __restrict__ W,
                       const float* __restrict__ att_src,
                       const float* __restrict__ att_dst,
                       float* __restrict__ a_s, float* __restrict__ a_d) {
    __shared__ float xs[16][GD];
    __shared__ float xpls[16][256];
    int t = threadIdx.x;
    int i0 = blockIdx.x * 16;
    #pragma unroll
    for (int s = 0; s < 2; s++) {
        int f = t + 256 * s;
        int r = f >> 5, c4 = (f & 31) << 2;
        *(float4*)&xs[r][c4] = *(const float4*)(x + (size_t)(i0 + r) * GD + c4);
    }
    __syncthreads();
    float acc[16];
    #pragma unroll
    for (int r = 0; r < 16; r++) acc[r] = 0.f;
    for (int d = 0; d < GD; d++) {
        float wv = W[d * 256 + t];
        #pragma unroll
        for (int r = 0; r < 16; r++) acc[r] += xs[r][d] * wv;
    }
    #pragma unroll
    for (int r = 0; r < 16; r++) xpls[r][t] = acc[r];
    __syncthreads();
    int wid = t >> 6, lane = t & 63;
    for (int jj = 0; jj < 8; jj++) {
        int job = wid * 8 + jj;
        int r = job >> 1, h = job & 1;
        float v0 = xpls[r][h * 128 + lane];
        float v1 = xpls[r][h * 128 + 64 + lane];
        float s = v0 * att_src[h * GD + lane] + v1 * att_src[h * GD + lane + 64];
        float d = v0 * att_dst[h * GD + lane] + v1 * att_dst[h * GD + lane + 64];
        s = wred(s); d = wred(d);
        if (lane == 0) { a_s[(i0 + r) * 2 + h] = s; a_d[(i0 + r) * 2 + h] = d; }
    }
}

// sorted top-6 of unsigned keys, branchless bubble insert
struct Top6 {
    unsigned a0, a1, a2, a3, a4, a5;
    __device__ __forceinline__ void init() { a0=a1=a2=a3=a4=a5=0xFFFFFFFFu; }
    __device__ __forceinline__ void insert(unsigned k) {
        unsigned m0 = umax2(a0, k);  a0 = umin2(a0, k);
        unsigned m1 = umax2(a1, m0); a1 = umin2(a1, m0);
        unsigned m2 = umax2(a2, m1); a2 = umin2(a2, m1);
        unsigned m3 = umax2(a3, m2); a3 = umin2(a3, m2);
        unsigned m4 = umax2(a4, m3); a4 = umin2(a4, m3);
        a5 = umin2(a5, m4);
    }
};

// MFMA candidate kNN. score'_ij = 512 + sq_i - 2 x_i.x_j (> 0 -> raw bits monotone).
__launch_bounds__(256, 2)
__global__ void k_gemm_topk(const unsigned short* __restrict__ xa,
                            const unsigned short* __restrict__ xb,
                            unsigned* __restrict__ cand) {
    __shared__ unsigned short At[18 * 128 * 8];
    int t = threadIdx.x;
    int w = t >> 6, lane = t & 63, h = lane >> 5, n = lane & 31;
    int col = blockIdx.x * 128 + w * 32 + n;
    int sb = blockIdx.y;

    short8 bfrag[9];
    #pragma unroll
    for (int kc = 0; kc < 9; kc++)
        bfrag[kc] = *(const short8*)(xb + (size_t)col * 144 + (2 * kc + h) * 8);

    Top6 T; T.init();

    for (int it = 0; it < 8; it++) {
        int rowbase = sb * 1024 + it * 128;
        __syncthreads();
        #pragma unroll
        for (int q = t; q < 18 * 128; q += 256) {
            int kb = q >> 7, r = q & 127;
            *(uint4*)&At[(kb * 128 + r) * 8] =
                *(const uint4*)(xa + (size_t)(rowbase + r) * 144 + kb * 8);
        }
        __syncthreads();

        float16 acc[4];
        #pragma unroll
        for (int rs = 0; rs < 4; rs++) acc[rs] = (float16)(0.f);

        #pragma unroll
        for (int kc = 0; kc < 9; kc++) {
            short8 a[4];
            #pragma unroll
            for (int rs = 0; rs < 4; rs++)
                a[rs] = *(const short8*)&At[((2 * kc + h) * 128 + rs * 32 + n) * 8];
            #pragma unroll
            for (int rs = 0; rs < 4; rs++)
                acc[rs] = __builtin_amdgcn_mfma_f32_32x32x16_bf16(a[rs], bfrag[kc], acc[rs], 0, 0, 0);
        }

        #pragma unroll
        for (int rs = 0; rs < 4; rs++) {
            float16 A = acc[rs];
            int rb = rowbase + 4 * h + rs * 32;
            unsigned kk[16];
            #pragma unroll
            for (int r = 0; r < 16; r++)
                kk[r] = (__float_as_uint(A[r]) & 0xFFFFE000u) |
                        (unsigned)(rb + (r & 3) + 8 * (r >> 2));
            unsigned ma = umin2(umin2(umin2(kk[0],kk[1]),umin2(kk[2],kk[3])),
                                umin2(umin2(kk[4],kk[5]),umin2(kk[6],kk[7])));
            unsigned mb = umin2(umin2(umin2(kk[8],kk[9]),umin2(kk[10],kk[11])),
                                umin2(umin2(kk[12],kk[13]),umin2(kk[14],kk[15])));
            if (umin2(ma, mb) <= T.a5) {
                #pragma unroll
                for (int r = 0; r < 16; r++) T.insert(kk[r]);
            }
        }
    }

    unsigned p0 = (unsigned)__shfl_xor((int)T.a0, 32), p1 = (unsigned)__shfl_xor((int)T.a1, 32),
             p2 = (unsigned)__shfl_xor((int)T.a2, 32), p3 = (unsigned)__shfl_xor((int)T.a3, 32),
             p4 = (unsigned)__shfl_xor((int)T.a4, 32), p5 = (unsigned)__shfl_xor((int)T.a5, 32);
    T.insert(p0); T.insert(p1); T.insert(p2); T.insert(p3); T.insert(p4); T.insert(p5);

    if (h == 0) {
        unsigned* c0 = cand + (size_t)col * 48 + sb * 6;
        c0[0]=T.a0; c0[1]=T.a1; c0[2]=T.a2; c0[3]=T.a3; c0[4]=T.a4; c0[5]=T.a5;
    }
}

__device__ __forceinline__ int clampN(int v) {
    return v < 0 ? 0 : (v >= GN ? GN - 1 : v);
}

// exact fp32 refine + degree count
__global__ void k_refine(const unsigned* __restrict__ cand,
                         const float* __restrict__ x, const float* __restrict__ sq,
                         int* __restrict__ fidx, int* __restrict__ cnt) {
    __shared__ float xjs[GD];
    __shared__ float dv[48];
    __shared__ int   di[48];
    int j = blockIdx.x, t = threadIdx.x;
    if (t < GD) xjs[t] = x[(size_t)j * GD + t];
    __syncthreads();
    int wv = t >> 6, lane = t & 63;
    for (int c = wv; c < 48; c += 4) {
        int idx = (int)(cand[(size_t)j * 48 + c] & 8191u);
        const float* xi = x + (size_t)idx * GD;
        float p = xjs[lane] * xi[lane] + xjs[lane + 64] * xi[lane + 64];
        p = wred(p);
        if (lane == 0) { dv[c] = sq[j] + sq[idx] - 2.f * p; di[c] = idx; }
    }
    __syncthreads();
    if (t == 0) {
        float v0 = 1e30f, v1 = 1e30f, v2 = 1e30f;
        int   i0 = 0x7fffffff, i1 = 0x7fffffff, i2 = 0x7fffffff;
        for (int c = 0; c < 48; c++) {
            float v = dv[c]; int id = di[c];
            if (v < v2 || (v == v2 && id < i2)) {
                if (v < v1 || (v == v1 && id < i1)) {
                    v2 = v1; i2 = i1;
                    if (v < v0 || (v == v0 && id < i0)) { v1 = v0; i1 = i0; v0 = v; i0 = id; }
                    else                                 { v1 = v; i1 = id; }
                } else { v2 = v; i2 = id; }
            }
        }
        i0 = clampN(i0); i1 = clampN(i1); i2 = clampN(i2);
        fidx[j * 3 + 0] = i0; fidx[j * 3 + 1] = i1; fidx[j * 3 + 2] = i2;
        atomicAdd(&cnt[i0], 1); atomicAdd(&cnt[i1], 1); atomicAdd(&cnt[i2], 1);
    }
}

__global__ void k_scan(const int* __restrict__ cnt, int* __restrict__ offs) {
    __shared__ int part[256];
    int t = threadIdx.x;
    int base = t * 32;
    int loc[32];
    int s = 0;
    #pragma unroll
    for (int k = 0; k < 32; k++) { loc[k] = s; s += cnt[base + k]; }
    part[t] = s;
    __syncthreads();
    if (t == 0) {
        int run = 0;
        for (int k = 0; k < 256; k++) { int v = part[k]; part[k] = run; run += v; }
        offs[GN] = run;
    }
    __syncthreads();
    int b = part[t];
    #pragma unroll
    for (int k = 0; k < 32; k++) offs[base + k] = b + loc[k];
}

__global__ void k_fill(const int* __restrict__ fidx, const int* __restrict__ offs,
                       int* __restrict__ cursor, int* __restrict__ elist) {
    int eid = blockIdx.x * 256 + threadIdx.x;
    int i = clampN(fidx[eid]);
    int pos = atomicAdd(&cursor[i], 1);
    int slot = offs[i] + pos;
    if (slot < GN * GK) elist[slot] = eid / 3;
}

// per-node softmax normalization: aw[k] = exp(e-m) per head; dens = 0.5/denom
__global__ void k_alpha(const int* __restrict__ offs, const int* __restrict__ elst,
                        const float* __restrict__ a_s, const float* __restrict__ a_d,
                        float2* __restrict__ aw, float2* __restrict__ dens) {
    int i = blockIdx.x * 256 + threadIdx.x;
    int s = offs[i], e = offs[i + 1];
    float ad0 = a_d[i * 2], ad1 = a_d[i * 2 + 1];
    float m0 = -1e30f, m1 = -1e30f;
    for (int k = s; k < e; k++) {
        int j = elst[k];
        float2 as = ((const float2*)a_s)[j];
        float e0 = as.x + ad0; e0 = e0 >= 0.f ? e0 : NEG_SLOPE * e0;
        float e1 = as.y + ad1; e1 = e1 >= 0.f ? e1 : NEG_SLOPE * e1;
        m0 = fmaxf(m0, e0); m1 = fmaxf(m1, e1);
    }
    float d0 = 0.f, d1 = 0.f;
    for (int k = s; k < e; k++) {
        int j = elst[k];
        float2 as = ((const float2*)a_s)[j];
        float e0 = as.x + ad0; e0 = e0 >= 0.f ? e0 : NEG_SLOPE * e0;
        float e1 = as.y + ad1; e1 = e1 >= 0.f ? e1 : NEG_SLOPE * e1;
        float w0 = expf(e0 - m0), w1 = expf(e1 - m1);
        d0 += w0; d1 += w1;
        aw[k] = make_float2(w0, w1);
    }
    dens[i] = make_float2(0.5f / d0, 0.5f / d1);
}

// fused: z-accumulate (wave per 4 nodes) -> GEMM (scalar-z broadcast, no spills)
// -> LN/ReLU/residual. launch_bounds caps at 128 VGPR (>=2 waves/SIMD).
__launch_bounds__(256, 2)
__global__ void k_out(const int* __restrict__ offs, const int* __restrict__ elst,
                      const float2* __restrict__ aw, const float2* __restrict__ dens,
                      const float* __restrict__ x, const float* __restrict__ W,
                      const float* __restrict__ bias, const float* __restrict__ gamma,
                      const float* __restrict__ beta, float* __restrict__ out) {
    __shared__ float zs[16][256];   // 16 KB: [row][h*128+d], z pre-scaled by 0.5/denom
    __shared__ float os[16][128];   // 8 KB
    int t = threadIdx.x, i0 = blockIdx.x * 16;
    int wv = t >> 6, lane = t & 63;

    // phase A: weighted neighbor sum (4 nodes per wave, independent edge loops)
    #pragma unroll
    for (int nn = 0; nn < 4; nn++) {
        int r = wv * 4 + nn, node = i0 + r;
        int s = offs[node], e = offs[node + 1];
        float z00 = 0.f, z01 = 0.f, z10 = 0.f, z11 = 0.f;
        for (int k = s; k < e; k++) {
            int j = elst[k];
            float2 al = aw[k];
            float xv0 = x[(size_t)j * GD + lane];
            float xv1 = x[(size_t)j * GD + 64 + lane];
            z00 += al.x * xv0; z01 += al.x * xv1;
            z10 += al.y * xv0; z11 += al.y * xv1;
        }
        float2 dn = dens[node];
        zs[r][lane]       = z00 * dn.x; zs[r][64 + lane]  = z01 * dn.x;
        zs[r][128 + lane] = z10 * dn.y; zs[r][192 + lane] = z11 * dn.y;
    }
    __syncthreads();

    // phase B: y[c] = bias[c] + sum_d z0[d]*W[d][c] + z1[d]*W[d][128+c]
    // scalar LDS z reads (wave-broadcast), coalesced W loads; 8 rows per thread-half.
    {
        int rh = t >> 7, c = t & 127;
        float acc[8];
        float bv = bias[c];
        #pragma unroll
        for (int r = 0; r < 8; r++) acc[r] = bv;
        for (int d = 0; d < GD; d++) {
            float w0 = W[d * 256 + c];
            float w1 = W[d * 256 + 128 + c];
            #pragma unroll
            for (int r = 0; r < 8; r++)
                acc[r] += zs[rh * 8 + r][d] * w0 + zs[rh * 8 + r][128 + d] * w1;
        }
        #pragma unroll
        for (int r = 0; r < 8; r++) os[rh * 8 + r][c] = acc[r];
    }
    __syncthreads();

    // phase C: LN + ReLU + residual
    #pragma unroll
    for (int nn = 0; nn < 4; nn++) {
        int r = wv * 4 + nn, node = i0 + r;
        float y0 = os[r][lane], y1 = os[r][lane + 64];
        float mu = wred(y0 + y1) * (1.f / 128.f);
        float c0 = y0 - mu, c1 = y1 - mu;
        float var = wred(c0 * c0 + c1 * c1) * (1.f / 128.f);
        float rs2 = 1.f / sqrtf(var + LN_EPS);
        float n0 = c0 * rs2 * gamma[lane] + beta[lane];
        float n1 = c1 * rs2 * gamma[lane + 64] + beta[lane + 64];
        n0 = n0 > 0.f ? n0 : 0.f;
        n1 = n1 > 0.f ? n1 : 0.f;
        out[(size_t)node * GD + lane]      = x[(size_t)node * GD + lane] + n0;
        out[(size_t)node * GD + lane + 64] = x[(size_t)node * GD + lane + 64] + n1;
    }
}

extern "C" void kernel_launch(void* const* d_in, const int* in_sizes, int n_in,
                              void* d_out, int out_size, void* d_ws, size_t ws_size,
                              hipStream_t stream) {
    const float* x       = (const float*)d_in[0];
    const float* W       = (const float*)d_in[2];
    const float* att_src = (const float*)d_in[3];
    const float* att_dst = (const float*)d_in[4];
    const float* bias    = (const float*)d_in[5];
    const float* gamma   = (const float*)d_in[6];
    const float* beta    = (const float*)d_in[7];
    float* out = (float*)d_out;

    char* w = (char*)d_ws;
    unsigned short* xa = (unsigned short*)w; w += (size_t)GN * 144 * 2;
    unsigned short* xb = (unsigned short*)w; w += (size_t)GN * 144 * 2;
    unsigned* cand = (unsigned*)w;           w += (size_t)GN * 48 * 4;
    float* sq   = (float*)w; w += (size_t)GN * 4;
    float* a_s  = (float*)w; w += (size_t)GN * GH * 4;
    float* a_d  = (float*)w; w += (size_t)GN * GH * 4;
    int*   fidx = (int*)w;   w += (size_t)GN * GK * 4;
    int*   cnt  = (int*)w;   w += (size_t)GN * 4;      // cnt|curs contiguous
    int*   curs = (int*)w;   w += (size_t)GN * 4;
    int*   offs = (int*)w;   w += (size_t)(GN + 1) * 4;
    int*   elst = (int*)w;   w += (size_t)GN * GK * 4;
    float2* aw  = (float2*)w; w += (size_t)GN * GK * 8;
    float2* dens = (float2*)w; w += (size_t)GN * 8;
    size_t need = (size_t)((char*)w - (char*)d_ws);
    if (ws_size < need) return;   // diagnostic guard

    k_zero<<<(2 * GN + 255) / 256, 256, 0, stream>>>(cnt, 2 * GN);
    k_conv<<<GN / 4, 256, 0, stream>>>(x, sq, xa, xb);
    k_attn<<<GN / 16, 256, 0, stream>>>(x, W, att_src, att_dst, a_s, a_d);
    k_gemm_topk<<<dim3(64, 8), 256, 0, stream>>>(xa, xb, cand);
    k_refine<<<GN, 256, 0, stream>>>(cand, x, sq, fidx, cnt);
    k_scan<<<1, 256, 0, stream>>>(cnt, offs);
    k_fill<<<GN * GK / 256, 256, 0, stream>>>(fidx, offs, curs, elst);
    k_alpha<<<GN / 256, 256, 0, stream>>>(offs, elst, a_s, a_d, aw, dens);
    k_out<<<GN / 16, 256, 0, stream>>>(offs, elst, aw, dens, x, W, bias, gamma, beta, out);
}

// Round 8
// 260.434 us; speedup vs baseline: 3.5415x; 1.2655x over previous
//
#include <hip/hip_runtime.h>
#include <hip/hip_bf16.h>
#include <math.h>

#define GN 8192
#define GD 128
#define GH 2
#define GK 3
#define NEG_SLOPE 0.2f
#define LN_EPS 1e-5f

using short8  = __attribute__((ext_vector_type(8)))  short;
using float16 = __attribute__((ext_vector_type(16))) float;

__device__ __forceinline__ float wred(float v) {
    #pragma unroll
    for (int o = 32; o > 0; o >>= 1) v += __shfl_xor(v, o, 64);
    return v;
}
__device__ __forceinline__ float wmax(float v) {
    #pragma unroll
    for (int o = 32; o > 0; o >>= 1) v = fmaxf(v, __shfl_xor(v, o, 64));
    return v;
}

__device__ __forceinline__ float rawbf2f(unsigned short s) {
    return __uint_as_float(((unsigned)s) << 16);
}
__device__ __forceinline__ unsigned short f2rawbf(float f) {
    __hip_bfloat16 b = __float2bfloat16(f);
    unsigned short r; __builtin_memcpy(&r, &b, 2);
    return r;
}
__device__ __forceinline__ unsigned umin2(unsigned a, unsigned b) { return a < b ? a : b; }
__device__ __forceinline__ unsigned umax2(unsigned a, unsigned b) { return a > b ? a : b; }

__global__ void k_zero(int* p, int n) {
    int t = blockIdx.x * 256 + threadIdx.x;
    if (t < n) p[t] = 0;
}

// one wave per row: sq[row], xa=[-2x bf16 | hi(sq+512) lo | 0..], xb=[x bf16 | 1 1 | 0..]
__global__ void k_conv(const float* __restrict__ x, float* __restrict__ sq,
                       unsigned short* __restrict__ xa, unsigned short* __restrict__ xb) {
    int row = blockIdx.x * 4 + (threadIdx.x >> 6);
    int lane = threadIdx.x & 63;
    const float* xr = x + (size_t)row * GD;
    float a0 = xr[lane], a1 = xr[lane + 64];
    float s = wred(a0 * a0 + a1 * a1);
    unsigned short* ar = xa + (size_t)row * 144;
    unsigned short* br = xb + (size_t)row * 144;
    ar[lane] = f2rawbf(-2.f * a0); ar[lane + 64] = f2rawbf(-2.f * a1);
    br[lane] = f2rawbf(a0);        br[lane + 64] = f2rawbf(a1);
    if (lane < 16) {
        unsigned short av = 0, bv = 0;
        if (lane == 0)      { av = f2rawbf(s + 512.f); bv = 0x3F80; }
        else if (lane == 1) { float hi = rawbf2f(f2rawbf(s + 512.f));
                              av = f2rawbf(s + 512.f - hi); bv = 0x3F80; }
        ar[128 + lane] = av; br[128 + lane] = bv;
        if (lane == 0) sq[row] = s;
    }
}

// fused xp = x@W and attention dots a_s,a_d; 16 nodes per block, col t per thread.
__global__ void k_attn(const float* __restrict__ x,
                       const float* __restrict__ W,
                       const float* __restrict__ att_src,
                       const float* __restrict__ att_dst,
                       float* __restrict__ a_s, float* __restrict__ a_d) {
    __shared__ float xs[16][GD];
    __shared__ float xpls[16][256];
    int t = threadIdx.x;
    int i0 = blockIdx.x * 16;
    #pragma unroll
    for (int s = 0; s < 2; s++) {
        int f = t + 256 * s;
        int r = f >> 5, c4 = (f & 31) << 2;
        *(float4*)&xs[r][c4] = *(const float4*)(x + (size_t)(i0 + r) * GD + c4);
    }
    __syncthreads();
    float acc[16];
    #pragma unroll
    for (int r = 0; r < 16; r++) acc[r] = 0.f;
    for (int d = 0; d < GD; d++) {
        float wv = W[d * 256 + t];
        #pragma unroll
        for (int r = 0; r < 16; r++) acc[r] += xs[r][d] * wv;
    }
    #pragma unroll
    for (int r = 0; r < 16; r++) xpls[r][t] = acc[r];
    __syncthreads();
    int wid = t >> 6, lane = t & 63;
    for (int jj = 0; jj < 8; jj++) {
        int job = wid * 8 + jj;
        int r = job >> 1, h = job & 1;
        float v0 = xpls[r][h * 128 + lane];
        float v1 = xpls[r][h * 128 + 64 + lane];
        float s = v0 * att_src[h * GD + lane] + v1 * att_src[h * GD + lane + 64];
        float d = v0 * att_dst[h * GD + lane] + v1 * att_dst[h * GD + lane + 64];
        s = wred(s); d = wred(d);
        if (lane == 0) { a_s[(i0 + r) * 2 + h] = s; a_d[(i0 + r) * 2 + h] = d; }
    }
}

// sorted top-6 of unsigned keys, branchless bubble insert
struct Top6 {
    unsigned a0, a1, a2, a3, a4, a5;
    __device__ __forceinline__ void init() { a0=a1=a2=a3=a4=a5=0xFFFFFFFFu; }
    __device__ __forceinline__ void insert(unsigned k) {
        unsigned m0 = umax2(a0, k);  a0 = umin2(a0, k);
        unsigned m1 = umax2(a1, m0); a1 = umin2(a1, m0);
        unsigned m2 = umax2(a2, m1); a2 = umin2(a2, m1);
        unsigned m3 = umax2(a3, m2); a3 = umin2(a3, m2);
        unsigned m4 = umax2(a4, m3); a4 = umin2(a4, m3);
        a5 = umin2(a5, m4);
    }
};

// MFMA candidate kNN. score'_ij = 512 + sq_i - 2 x_i.x_j (> 0 -> raw bits monotone).
__launch_bounds__(256, 2)
__global__ void k_gemm_topk(const unsigned short* __restrict__ xa,
                            const unsigned short* __restrict__ xb,
                            unsigned* __restrict__ cand) {
    __shared__ unsigned short At[18 * 128 * 8];
    int t = threadIdx.x;
    int w = t >> 6, lane = t & 63, h = lane >> 5, n = lane & 31;
    int col = blockIdx.x * 128 + w * 32 + n;
    int sb = blockIdx.y;

    short8 bfrag[9];
    #pragma unroll
    for (int kc = 0; kc < 9; kc++)
        bfrag[kc] = *(const short8*)(xb + (size_t)col * 144 + (2 * kc + h) * 8);

    Top6 T; T.init();

    for (int it = 0; it < 8; it++) {
        int rowbase = sb * 1024 + it * 128;
        __syncthreads();
        #pragma unroll
        for (int q = t; q < 18 * 128; q += 256) {
            int kb = q >> 7, r = q & 127;
            *(uint4*)&At[(kb * 128 + r) * 8] =
                *(const uint4*)(xa + (size_t)(rowbase + r) * 144 + kb * 8);
        }
        __syncthreads();

        float16 acc[4];
        #pragma unroll
        for (int rs = 0; rs < 4; rs++) acc[rs] = (float16)(0.f);

        #pragma unroll
        for (int kc = 0; kc < 9; kc++) {
            short8 a[4];
            #pragma unroll
            for (int rs = 0; rs < 4; rs++)
                a[rs] = *(const short8*)&At[((2 * kc + h) * 128 + rs * 32 + n) * 8];
            #pragma unroll
            for (int rs = 0; rs < 4; rs++)
                acc[rs] = __builtin_amdgcn_mfma_f32_32x32x16_bf16(a[rs], bfrag[kc], acc[rs], 0, 0, 0);
        }

        #pragma unroll
        for (int rs = 0; rs < 4; rs++) {
            float16 A = acc[rs];
            int rb = rowbase + 4 * h + rs * 32;
            unsigned kk[16];
            #pragma unroll
            for (int r = 0; r < 16; r++)
                kk[r] = (__float_as_uint(A[r]) & 0xFFFFE000u) |
                        (unsigned)(rb + (r & 3) + 8 * (r >> 2));
            unsigned ma = umin2(umin2(umin2(kk[0],kk[1]),umin2(kk[2],kk[3])),
                                umin2(umin2(kk[4],kk[5]),umin2(kk[6],kk[7])));
            unsigned mb = umin2(umin2(umin2(kk[8],kk[9]),umin2(kk[10],kk[11])),
                                umin2(umin2(kk[12],kk[13]),umin2(kk[14],kk[15])));
            if (umin2(ma, mb) <= T.a5) {
                #pragma unroll
                for (int r = 0; r < 16; r++) T.insert(kk[r]);
            }
        }
    }

    unsigned p0 = (unsigned)__shfl_xor((int)T.a0, 32), p1 = (unsigned)__shfl_xor((int)T.a1, 32),
             p2 = (unsigned)__shfl_xor((int)T.a2, 32), p3 = (unsigned)__shfl_xor((int)T.a3, 32),
             p4 = (unsigned)__shfl_xor((int)T.a4, 32), p5 = (unsigned)__shfl_xor((int)T.a5, 32);
    T.insert(p0); T.insert(p1); T.insert(p2); T.insert(p3); T.insert(p4); T.insert(p5);

    if (h == 0) {
        unsigned* c0 = cand + (size_t)col * 48 + sb * 6;
        c0[0]=T.a0; c0[1]=T.a1; c0[2]=T.a2; c0[3]=T.a3; c0[4]=T.a4; c0[5]=T.a5;
    }
}

__device__ __forceinline__ int clampN(int v) {
    return v < 0 ? 0 : (v >= GN ? GN - 1 : v);
}

// exact fp32 refine + degree count
__global__ void k_refine(const unsigned* __restrict__ cand,
                         const float* __restrict__ x, const float* __restrict__ sq,
                         int* __restrict__ fidx, int* __restrict__ cnt) {
    __shared__ float xjs[GD];
    __shared__ float dv[48];
    __shared__ int   di[48];
    int j = blockIdx.x, t = threadIdx.x;
    if (t < GD) xjs[t] = x[(size_t)j * GD + t];
    __syncthreads();
    int wv = t >> 6, lane = t & 63;
    for (int c = wv; c < 48; c += 4) {
        int idx = (int)(cand[(size_t)j * 48 + c] & 8191u);
        const float* xi = x + (size_t)idx * GD;
        float p = xjs[lane] * xi[lane] + xjs[lane + 64] * xi[lane + 64];
        p = wred(p);
        if (lane == 0) { dv[c] = sq[j] + sq[idx] - 2.f * p; di[c] = idx; }
    }
    __syncthreads();
    if (t == 0) {
        float v0 = 1e30f, v1 = 1e30f, v2 = 1e30f;
        int   i0 = 0x7fffffff, i1 = 0x7fffffff, i2 = 0x7fffffff;
        for (int c = 0; c < 48; c++) {
            float v = dv[c]; int id = di[c];
            if (v < v2 || (v == v2 && id < i2)) {
                if (v < v1 || (v == v1 && id < i1)) {
                    v2 = v1; i2 = i1;
                    if (v < v0 || (v == v0 && id < i0)) { v1 = v0; i1 = i0; v0 = v; i0 = id; }
                    else                                 { v1 = v; i1 = id; }
                } else { v2 = v; i2 = id; }
            }
        }
        i0 = clampN(i0); i1 = clampN(i1); i2 = clampN(i2);
        fidx[j * 3 + 0] = i0; fidx[j * 3 + 1] = i1; fidx[j * 3 + 2] = i2;
        atomicAdd(&cnt[i0], 1); atomicAdd(&cnt[i1], 1); atomicAdd(&cnt[i2], 1);
    }
}

__global__ void k_scan(const int* __restrict__ cnt, int* __restrict__ offs) {
    __shared__ int part[256];
    int t = threadIdx.x;
    int base = t * 32;
    int loc[32];
    int s = 0;
    #pragma unroll
    for (int k = 0; k < 32; k++) { loc[k] = s; s += cnt[base + k]; }
    part[t] = s;
    __syncthreads();
    if (t == 0) {
        int run = 0;
        for (int k = 0; k < 256; k++) { int v = part[k]; part[k] = run; run += v; }
        offs[GN] = run;
    }
    __syncthreads();
    int b = part[t];
    #pragma unroll
    for (int k = 0; k < 32; k++) offs[base + k] = b + loc[k];
}

// edge-parallel fill: CSR scatter + per-edge leaky-relu'd logits ew[slot]
__global__ void k_fill(const int* __restrict__ fidx, const int* __restrict__ offs,
                       int* __restrict__ cursor, int* __restrict__ elist,
                       const float* __restrict__ a_s, const float* __restrict__ a_d,
                       float2* __restrict__ ew) {
    int eid = blockIdx.x * 256 + threadIdx.x;
    int i = clampN(fidx[eid]);
    int src = eid / 3;
    float2 as = ((const float2*)a_s)[src];
    float2 ad = ((const float2*)a_d)[i];
    float e0 = as.x + ad.x; e0 = e0 >= 0.f ? e0 : NEG_SLOPE * e0;
    float e1 = as.y + ad.y; e1 = e1 >= 0.f ? e1 : NEG_SLOPE * e1;
    int pos = atomicAdd(&cursor[i], 1);
    int slot = offs[i] + pos;
    if (slot < GN * GK) { elist[slot] = src; ew[slot] = make_float2(e0, e1); }
}

// fused: in-wave softmax stats -> z-accumulate (wave per 4 nodes) -> GEMM
// (scalar-z broadcast) -> LN/ReLU/residual.
__launch_bounds__(256, 2)
__global__ void k_out(const int* __restrict__ offs, const int* __restrict__ elst,
                      const float2* __restrict__ ew,
                      const float* __restrict__ x, const float* __restrict__ W,
                      const float* __restrict__ bias, const float* __restrict__ gamma,
                      const float* __restrict__ beta, float* __restrict__ out) {
    __shared__ float zs[16][256];   // 16 KB: [row][h*128+d], z pre-scaled by 0.5/denom
    __shared__ float os[16][128];   // 8 KB
    int t = threadIdx.x, i0 = blockIdx.x * 16;
    int wv = t >> 6, lane = t & 63;

    // phase A: per-node softmax stats (in-wave) + weighted neighbor sum
    #pragma unroll
    for (int nn = 0; nn < 4; nn++) {
        int r = wv * 4 + nn, node = i0 + r;
        int s = offs[node], e = offs[node + 1];
        // stats: lanes strided over edges (deg>=1 via self-edge)
        float m0 = -1e30f, m1 = -1e30f;
        for (int k = s + lane; k < e; k += 64) {
            float2 v = ew[k];
            m0 = fmaxf(m0, v.x); m1 = fmaxf(m1, v.y);
        }
        m0 = wmax(m0); m1 = wmax(m1);
        float s0 = 0.f, s1 = 0.f;
        for (int k = s + lane; k < e; k += 64) {
            float2 v = ew[k];
            s0 += expf(v.x - m0); s1 += expf(v.y - m1);
        }
        s0 = wred(s0); s1 = wred(s1);
        float dn0 = 0.5f / s0, dn1 = 0.5f / s1;

        float z00 = 0.f, z01 = 0.f, z10 = 0.f, z11 = 0.f;
        for (int k = s; k < e; k++) {
            int j = elst[k];              // wave-uniform broadcast load
            float2 v = ew[k];
            float w0 = expf(v.x - m0), w1 = expf(v.y - m1);
            float xv0 = x[(size_t)j * GD + lane];
            float xv1 = x[(size_t)j * GD + 64 + lane];
            z00 += w0 * xv0; z01 += w0 * xv1;
            z10 += w1 * xv0; z11 += w1 * xv1;
        }
        zs[r][lane]       = z00 * dn0; zs[r][64 + lane]  = z01 * dn0;
        zs[r][128 + lane] = z10 * dn1; zs[r][192 + lane] = z11 * dn1;
    }
    __syncthreads();

    // phase B: y[c] = bias[c] + sum_d z0[d]*W[d][c] + z1[d]*W[d][128+c]
    {
        int rh = t >> 7, c = t & 127;
        float acc[8];
        float bv = bias[c];
        #pragma unroll
        for (int r = 0; r < 8; r++) acc[r] = bv;
        for (int d = 0; d < GD; d++) {
            float w0 = W[d * 256 + c];
            float w1 = W[d * 256 + 128 + c];
            #pragma unroll
            for (int r = 0; r < 8; r++)
                acc[r] += zs[rh * 8 + r][d] * w0 + zs[rh * 8 + r][128 + d] * w1;
        }
        #pragma unroll
        for (int r = 0; r < 8; r++) os[rh * 8 + r][c] = acc[r];
    }
    __syncthreads();

    // phase C: LN + ReLU + residual
    #pragma unroll
    for (int nn = 0; nn < 4; nn++) {
        int r = wv * 4 + nn, node = i0 + r;
        float y0 = os[r][lane], y1 = os[r][lane + 64];
        float mu = wred(y0 + y1) * (1.f / 128.f);
        float c0 = y0 - mu, c1 = y1 - mu;
        float var = wred(c0 * c0 + c1 * c1) * (1.f / 128.f);
        float rs2 = 1.f / sqrtf(var + LN_EPS);
        float n0 = c0 * rs2 * gamma[lane] + beta[lane];
        float n1 = c1 * rs2 * gamma[lane + 64] + beta[lane + 64];
        n0 = n0 > 0.f ? n0 : 0.f;
        n1 = n1 > 0.f ? n1 : 0.f;
        out[(size_t)node * GD + lane]      = x[(size_t)node * GD + lane] + n0;
        out[(size_t)node * GD + lane + 64] = x[(size_t)node * GD + lane + 64] + n1;
    }
}

extern "C" void kernel_launch(void* const* d_in, const int* in_sizes, int n_in,
                              void* d_out, int out_size, void* d_ws, size_t ws_size,
                              hipStream_t stream) {
    const float* x       = (const float*)d_in[0];
    const float* W       = (const float*)d_in[2];
    const float* att_src = (const float*)d_in[3];
    const float* att_dst = (const float*)d_in[4];
    const float* bias    = (const float*)d_in[5];
    const float* gamma   = (const float*)d_in[6];
    const float* beta    = (const float*)d_in[7];
    float* out = (float*)d_out;

    char* w = (char*)d_ws;
    unsigned short* xa = (unsigned short*)w; w += (size_t)GN * 144 * 2;
    unsigned short* xb = (unsigned short*)w; w += (size_t)GN * 144 * 2;
    unsigned* cand = (unsigned*)w;           w += (size_t)GN * 48 * 4;
    float2* ew  = (float2*)w; w += (size_t)GN * GK * 8;
    float* sq   = (float*)w; w += (size_t)GN * 4;
    float* a_s  = (float*)w; w += (size_t)GN * GH * 4;
    float* a_d  = (float*)w; w += (size_t)GN * GH * 4;
    int*   fidx = (int*)w;   w += (size_t)GN * GK * 4;
    int*   cnt  = (int*)w;   w += (size_t)GN * 4;      // cnt|curs contiguous
    int*   curs = (int*)w;   w += (size_t)GN * 4;
    int*   offs = (int*)w;   w += (size_t)(GN + 1) * 4;
    int*   elst = (int*)w;   w += (size_t)GN * GK * 4;
    size_t need = (size_t)((char*)w - (char*)d_ws);
    if (ws_size < need) return;   // diagnostic guard

    k_zero<<<(2 * GN + 255) / 256, 256, 0, stream>>>(cnt, 2 * GN);
    k_conv<<<GN / 4, 256, 0, stream>>>(x, sq, xa, xb);
    k_attn<<<GN / 16, 256, 0, stream>>>(x, W, att_src, att_dst, a_s, a_d);
    k_gemm_topk<<<dim3(64, 8), 256, 0, stream>>>(xa, xb, cand);
    k_refine<<<GN, 256, 0, stream>>>(cand, x, sq, fidx, cnt);
    k_scan<<<1, 256, 0, stream>>>(cnt, offs);
    k_fill<<<GN * GK / 256, 256, 0, stream>>>(fidx, offs, curs, elst, a_s, a_d, ew);
    k_out<<<GN / 16, 256, 0, stream>>>(offs, elst, ew, x, W, bias, gamma, beta, out);
}

// Round 9
// 241.896 us; speedup vs baseline: 3.8129x; 1.0766x over previous
//
#include <hip/hip_runtime.h>
#include <hip/hip_bf16.h>
#include <math.h>

#define GN 8192
#define GD 128
#define GH 2
#define GK 3
#define NEG_SLOPE 0.2f
#define LN_EPS 1e-5f

using short8  = __attribute__((ext_vector_type(8)))  short;
using float16 = __attribute__((ext_vector_type(16))) float;
using f32x4   = __attribute__((ext_vector_type(4)))  float;

__device__ __forceinline__ float wred(float v) {
    #pragma unroll
    for (int o = 32; o > 0; o >>= 1) v += __shfl_xor(v, o, 64);
    return v;
}
__device__ __forceinline__ float wmax(float v) {
    #pragma unroll
    for (int o = 32; o > 0; o >>= 1) v = fmaxf(v, __shfl_xor(v, o, 64));
    return v;
}

__device__ __forceinline__ float rawbf2f(unsigned short s) {
    return __uint_as_float(((unsigned)s) << 16);
}
__device__ __forceinline__ unsigned short f2rawbf(float f) {
    __hip_bfloat16 b = __float2bfloat16(f);
    unsigned short r; __builtin_memcpy(&r, &b, 2);
    return r;
}
__device__ __forceinline__ unsigned umin2(unsigned a, unsigned b) { return a < b ? a : b; }
__device__ __forceinline__ unsigned umax2(unsigned a, unsigned b) { return a > b ? a : b; }

__global__ void k_zero(int* p, int n) {
    int t = blockIdx.x * 256 + threadIdx.x;
    if (t < n) p[t] = 0;
}

// u vectors: uvec[b][d] = sum_c W[d][h*128+c] * v[h][c], b = {s0,s1,d0,d1}
__global__ void k_uvec(const float* __restrict__ W, const float* __restrict__ att_src,
                       const float* __restrict__ att_dst, float* __restrict__ uvec) {
    __shared__ float vs[128];
    int b = blockIdx.x, t = threadIdx.x;
    int h = b & 1;
    const float* v = (b < 2 ? att_src : att_dst) + h * 128;
    if (t < 128) vs[t] = v[t];
    __syncthreads();
    int d = t >> 1, half = t & 1;
    const float* wr = W + (size_t)d * 256 + h * 128 + half * 64;
    float s = 0.f;
    for (int c = 0; c < 64; c++) s += wr[c] * vs[half * 64 + c];
    s += __shfl_xor(s, 1, 64);
    if (half == 0) uvec[b * 128 + d] = s;
}

// W transpose into MFMA-B layout: Wt[c][k], k = h*128+d, bf16 hi/lo split
__global__ void k_trans(const float* __restrict__ W,
                        unsigned short* __restrict__ Wth, unsigned short* __restrict__ Wtl) {
    int e = blockIdx.x * 256 + threadIdx.x;   // 32768
    int d = e >> 8, j = e & 255;
    int h = j >> 7, c = j & 127;
    int k = h * 128 + d;
    float w = W[e];
    unsigned short hi = f2rawbf(w);
    Wth[c * 256 + k] = hi;
    Wtl[c * 256 + k] = f2rawbf(w - rawbf2f(hi));
}

// one wave per row: sq, xa=[-2x | hi(sq+512) lo | 0..], xb=[x | 1 1 | 0..],
// plus attention dots a_s/a_d via u-vectors (k_attn eliminated).
__global__ void k_conv(const float* __restrict__ x, const float* __restrict__ uvec,
                       float* __restrict__ sq,
                       unsigned short* __restrict__ xa, unsigned short* __restrict__ xb,
                       float* __restrict__ a_s, float* __restrict__ a_d) {
    int row = blockIdx.x * 4 + (threadIdx.x >> 6);
    int lane = threadIdx.x & 63;
    const float* xr = x + (size_t)row * GD;
    float a0 = xr[lane], a1 = xr[lane + 64];
    float s = wred(a0 * a0 + a1 * a1);
    unsigned short* ar = xa + (size_t)row * 144;
    unsigned short* br = xb + (size_t)row * 144;
    ar[lane] = f2rawbf(-2.f * a0); ar[lane + 64] = f2rawbf(-2.f * a1);
    br[lane] = f2rawbf(a0);        br[lane + 64] = f2rawbf(a1);
    float s0 = wred(a0 * uvec[lane]       + a1 * uvec[64 + lane]);
    float s1 = wred(a0 * uvec[128 + lane] + a1 * uvec[192 + lane]);
    float d0 = wred(a0 * uvec[256 + lane] + a1 * uvec[320 + lane]);
    float d1 = wred(a0 * uvec[384 + lane] + a1 * uvec[448 + lane]);
    if (lane < 16) {
        unsigned short av = 0, bv = 0;
        if (lane == 0)      { av = f2rawbf(s + 512.f); bv = 0x3F80; }
        else if (lane == 1) { float hi = rawbf2f(f2rawbf(s + 512.f));
                              av = f2rawbf(s + 512.f - hi); bv = 0x3F80; }
        ar[128 + lane] = av; br[128 + lane] = bv;
        if (lane == 0) {
            sq[row] = s;
            a_s[row * 2] = s0; a_s[row * 2 + 1] = s1;
            a_d[row * 2] = d0; a_d[row * 2 + 1] = d1;
        }
    }
}

// sorted top-6 of unsigned keys, branchless bubble insert
struct Top6 {
    unsigned a0, a1, a2, a3, a4, a5;
    __device__ __forceinline__ void init() { a0=a1=a2=a3=a4=a5=0xFFFFFFFFu; }
    __device__ __forceinline__ void insert(unsigned k) {
        unsigned m0 = umax2(a0, k);  a0 = umin2(a0, k);
        unsigned m1 = umax2(a1, m0); a1 = umin2(a1, m0);
        unsigned m2 = umax2(a2, m1); a2 = umin2(a2, m1);
        unsigned m3 = umax2(a3, m2); a3 = umin2(a3, m2);
        unsigned m4 = umax2(a4, m3); a4 = umin2(a4, m3);
        a5 = umin2(a5, m4);
    }
};

// MFMA candidate kNN. score'_ij = 512 + sq_i - 2 x_i.x_j (> 0 -> raw bits monotone).
__launch_bounds__(256, 2)
__global__ void k_gemm_topk(const unsigned short* __restrict__ xa,
                            const unsigned short* __restrict__ xb,
                            unsigned* __restrict__ cand) {
    __shared__ unsigned short At[18 * 128 * 8];
    int t = threadIdx.x;
    int w = t >> 6, lane = t & 63, h = lane >> 5, n = lane & 31;
    int col = blockIdx.x * 128 + w * 32 + n;
    int sb = blockIdx.y;

    short8 bfrag[9];
    #pragma unroll
    for (int kc = 0; kc < 9; kc++)
        bfrag[kc] = *(const short8*)(xb + (size_t)col * 144 + (2 * kc + h) * 8);

    Top6 T; T.init();

    for (int it = 0; it < 8; it++) {
        int rowbase = sb * 1024 + it * 128;
        __syncthreads();
        #pragma unroll
        for (int q = t; q < 18 * 128; q += 256) {
            int kb = q >> 7, r = q & 127;
            *(uint4*)&At[(kb * 128 + r) * 8] =
                *(const uint4*)(xa + (size_t)(rowbase + r) * 144 + kb * 8);
        }
        __syncthreads();

        float16 acc[4];
        #pragma unroll
        for (int rs = 0; rs < 4; rs++) acc[rs] = (float16)(0.f);

        #pragma unroll
        for (int kc = 0; kc < 9; kc++) {
            short8 a[4];
            #pragma unroll
            for (int rs = 0; rs < 4; rs++)
                a[rs] = *(const short8*)&At[((2 * kc + h) * 128 + rs * 32 + n) * 8];
            #pragma unroll
            for (int rs = 0; rs < 4; rs++)
                acc[rs] = __builtin_amdgcn_mfma_f32_32x32x16_bf16(a[rs], bfrag[kc], acc[rs], 0, 0, 0);
        }

        #pragma unroll
        for (int rs = 0; rs < 4; rs++) {
            float16 A = acc[rs];
            int rb = rowbase + 4 * h + rs * 32;
            unsigned kk[16];
            #pragma unroll
            for (int r = 0; r < 16; r++)
                kk[r] = (__float_as_uint(A[r]) & 0xFFFFE000u) |
                        (unsigned)(rb + (r & 3) + 8 * (r >> 2));
            unsigned ma = umin2(umin2(umin2(kk[0],kk[1]),umin2(kk[2],kk[3])),
                                umin2(umin2(kk[4],kk[5]),umin2(kk[6],kk[7])));
            unsigned mb = umin2(umin2(umin2(kk[8],kk[9]),umin2(kk[10],kk[11])),
                                umin2(umin2(kk[12],kk[13]),umin2(kk[14],kk[15])));
            if (umin2(ma, mb) <= T.a5) {
                #pragma unroll
                for (int r = 0; r < 16; r++) T.insert(kk[r]);
            }
        }
    }

    unsigned p0 = (unsigned)__shfl_xor((int)T.a0, 32), p1 = (unsigned)__shfl_xor((int)T.a1, 32),
             p2 = (unsigned)__shfl_xor((int)T.a2, 32), p3 = (unsigned)__shfl_xor((int)T.a3, 32),
             p4 = (unsigned)__shfl_xor((int)T.a4, 32), p5 = (unsigned)__shfl_xor((int)T.a5, 32);
    T.insert(p0); T.insert(p1); T.insert(p2); T.insert(p3); T.insert(p4); T.insert(p5);

    if (h == 0) {
        unsigned* c0 = cand + (size_t)col * 48 + sb * 6;
        c0[0]=T.a0; c0[1]=T.a1; c0[2]=T.a2; c0[3]=T.a3; c0[4]=T.a4; c0[5]=T.a5;
    }
}

__device__ __forceinline__ int clampN(int v) {
    return v < 0 ? 0 : (v >= GN ? GN - 1 : v);
}

// exact fp32 refine + degree count
__global__ void k_refine(const unsigned* __restrict__ cand,
                         const float* __restrict__ x, const float* __restrict__ sq,
                         int* __restrict__ fidx, int* __restrict__ cnt) {
    __shared__ float xjs[GD];
    __shared__ float dv[48];
    __shared__ int   di[48];
    int j = blockIdx.x, t = threadIdx.x;
    if (t < GD) xjs[t] = x[(size_t)j * GD + t];
    __syncthreads();
    int wv = t >> 6, lane = t & 63;
    for (int c = wv; c < 48; c += 4) {
        int idx = (int)(cand[(size_t)j * 48 + c] & 8191u);
        const float* xi = x + (size_t)idx * GD;
        float p = xjs[lane] * xi[lane] + xjs[lane + 64] * xi[lane + 64];
        p = wred(p);
        if (lane == 0) { dv[c] = sq[j] + sq[idx] - 2.f * p; di[c] = idx; }
    }
    __syncthreads();
    if (t == 0) {
        float v0 = 1e30f, v1 = 1e30f, v2 = 1e30f;
        int   i0 = 0x7fffffff, i1 = 0x7fffffff, i2 = 0x7fffffff;
        for (int c = 0; c < 48; c++) {
            float v = dv[c]; int id = di[c];
            if (v < v2 || (v == v2 && id < i2)) {
                if (v < v1 || (v == v1 && id < i1)) {
                    v2 = v1; i2 = i1;
                    if (v < v0 || (v == v0 && id < i0)) { v1 = v0; i1 = i0; v0 = v; i0 = id; }
                    else                                 { v1 = v; i1 = id; }
                } else { v2 = v; i2 = id; }
            }
        }
        i0 = clampN(i0); i1 = clampN(i1); i2 = clampN(i2);
        fidx[j * 3 + 0] = i0; fidx[j * 3 + 1] = i1; fidx[j * 3 + 2] = i2;
        atomicAdd(&cnt[i0], 1); atomicAdd(&cnt[i1], 1); atomicAdd(&cnt[i2], 1);
    }
}

__global__ void k_scan(const int* __restrict__ cnt, int* __restrict__ offs) {
    __shared__ int part[256];
    int t = threadIdx.x;
    int base = t * 32;
    int loc[32];
    int s = 0;
    #pragma unroll
    for (int k = 0; k < 32; k++) { loc[k] = s; s += cnt[base + k]; }
    part[t] = s;
    __syncthreads();
    if (t == 0) {
        int run = 0;
        for (int k = 0; k < 256; k++) { int v = part[k]; part[k] = run; run += v; }
        offs[GN] = run;
    }
    __syncthreads();
    int b = part[t];
    #pragma unroll
    for (int k = 0; k < 32; k++) offs[base + k] = b + loc[k];
}

// edge-parallel fill: CSR scatter + per-edge leaky-relu'd logits ew[slot]
__global__ void k_fill(const int* __restrict__ fidx, const int* __restrict__ offs,
                       int* __restrict__ cursor, int* __restrict__ elist,
                       const float* __restrict__ a_s, const float* __restrict__ a_d,
                       float2* __restrict__ ew) {
    int eid = blockIdx.x * 256 + threadIdx.x;
    int i = clampN(fidx[eid]);
    int src = eid / 3;
    float2 as = ((const float2*)a_s)[src];
    float2 ad = ((const float2*)a_d)[i];
    float e0 = as.x + ad.x; e0 = e0 >= 0.f ? e0 : NEG_SLOPE * e0;
    float e1 = as.y + ad.y; e1 = e1 >= 0.f ? e1 : NEG_SLOPE * e1;
    int pos = atomicAdd(&cursor[i], 1);
    int slot = offs[i] + pos;
    if (slot < GN * GK) { elist[slot] = src; ew[slot] = make_float2(e0, e1); }
}

// fused: in-wave softmax stats + z-accumulate -> MFMA GEMM y = z@Wt (err-compensated
// bf16 hi/lo) -> bias + LN + ReLU + residual.
__launch_bounds__(256, 2)
__global__ void k_out(const int* __restrict__ offs, const int* __restrict__ elst,
                      const float2* __restrict__ ew,
                      const float* __restrict__ x,
                      const unsigned short* __restrict__ Wth,
                      const unsigned short* __restrict__ Wtl,
                      const float* __restrict__ bias, const float* __restrict__ gamma,
                      const float* __restrict__ beta, float* __restrict__ out) {
    __shared__ unsigned short zh[16][264];  // A-frag layout, +8 pad (16B-aligned rows)
    __shared__ unsigned short zl[16][264];
    __shared__ float os[16][132];
    int t = threadIdx.x, i0 = blockIdx.x * 16;
    int wv = t >> 6, lane = t & 63;

    // phase A: per-node softmax stats (in-wave) + weighted neighbor sum -> bf16 hi/lo
    #pragma unroll
    for (int pp = 0; pp < 4; pp++) {
        int r = wv * 4 + pp, node = i0 + r;
        int s = offs[node], e = offs[node + 1];
        float m0 = -1e30f, m1 = -1e30f;
        for (int k = s + lane; k < e; k += 64) {
            float2 v = ew[k];
            m0 = fmaxf(m0, v.x); m1 = fmaxf(m1, v.y);
        }
        m0 = wmax(m0); m1 = wmax(m1);
        float s0 = 0.f, s1 = 0.f;
        for (int k = s + lane; k < e; k += 64) {
            float2 v = ew[k];
            s0 += expf(v.x - m0); s1 += expf(v.y - m1);
        }
        s0 = wred(s0); s1 = wred(s1);
        float dn0 = 0.5f / s0, dn1 = 0.5f / s1;

        float z00 = 0.f, z01 = 0.f, z10 = 0.f, z11 = 0.f;
        for (int k = s; k < e; k++) {
            int j = elst[k];
            float2 v = ew[k];
            float w0 = expf(v.x - m0), w1 = expf(v.y - m1);
            float xv0 = x[(size_t)j * GD + lane];
            float xv1 = x[(size_t)j * GD + 64 + lane];
            z00 += w0 * xv0; z01 += w0 * xv1;
            z10 += w1 * xv0; z11 += w1 * xv1;
        }
        float v0 = z00 * dn0, v1 = z01 * dn0, v2 = z10 * dn1, v3 = z11 * dn1;
        unsigned short h0 = f2rawbf(v0), h1 = f2rawbf(v1), h2 = f2rawbf(v2), h3 = f2rawbf(v3);
        zh[r][lane]       = h0; zl[r][lane]       = f2rawbf(v0 - rawbf2f(h0));
        zh[r][64 + lane]  = h1; zl[r][64 + lane]  = f2rawbf(v1 - rawbf2f(h1));
        zh[r][128 + lane] = h2; zl[r][128 + lane] = f2rawbf(v2 - rawbf2f(h2));
        zh[r][192 + lane] = h3; zl[r][192 + lane] = f2rawbf(v3 - rawbf2f(h3));
    }
    __syncthreads();

    // phase B: y[16 nodes][128 cols] = z[16][256] @ Wt[256][128] via 16x16x32 MFMA.
    // err-comp: Ah*Bh + Al*Bh + Ah*Bl (rel err ~1e-4)
    {
        int qd = lane >> 4, an = lane & 15;
        int c0 = wv * 32 + an, c1 = wv * 32 + 16 + an;
        f32x4 acc0 = {0.f, 0.f, 0.f, 0.f}, acc1 = {0.f, 0.f, 0.f, 0.f};
        #pragma unroll
        for (int s = 0; s < 8; s++) {
            int ko = s * 32 + qd * 8;
            short8 ah = *(const short8*)&zh[an][ko];
            short8 al = *(const short8*)&zl[an][ko];
            short8 bh0 = *(const short8*)(Wth + (size_t)c0 * 256 + ko);
            short8 bl0 = *(const short8*)(Wtl + (size_t)c0 * 256 + ko);
            short8 bh1 = *(const short8*)(Wth + (size_t)c1 * 256 + ko);
            short8 bl1 = *(const short8*)(Wtl + (size_t)c1 * 256 + ko);
            acc0 = __builtin_amdgcn_mfma_f32_16x16x32_bf16(ah, bh0, acc0, 0, 0, 0);
            acc0 = __builtin_amdgcn_mfma_f32_16x16x32_bf16(al, bh0, acc0, 0, 0, 0);
            acc0 = __builtin_amdgcn_mfma_f32_16x16x32_bf16(ah, bl0, acc0, 0, 0, 0);
            acc1 = __builtin_amdgcn_mfma_f32_16x16x32_bf16(ah, bh1, acc1, 0, 0, 0);
            acc1 = __builtin_amdgcn_mfma_f32_16x16x32_bf16(al, bh1, acc1, 0, 0, 0);
            acc1 = __builtin_amdgcn_mfma_f32_16x16x32_bf16(ah, bl1, acc1, 0, 0, 0);
        }
        #pragma unroll
        for (int r = 0; r < 4; r++) {
            os[qd * 4 + r][c0] = acc0[r];
            os[qd * 4 + r][c1] = acc1[r];
        }
    }
    __syncthreads();

    // phase C: bias + LN + ReLU + residual
    #pragma unroll
    for (int pp = 0; pp < 4; pp++) {
        int r = wv * 4 + pp, node = i0 + r;
        float y0 = os[r][lane] + bias[lane];
        float y1 = os[r][lane + 64] + bias[lane + 64];
        float mu = wred(y0 + y1) * (1.f / 128.f);
        float c0 = y0 - mu, c1 = y1 - mu;
        float var = wred(c0 * c0 + c1 * c1) * (1.f / 128.f);
        float rs2 = 1.f / sqrtf(var + LN_EPS);
        float n0 = c0 * rs2 * gamma[lane] + beta[lane];
        float n1 = c1 * rs2 * gamma[lane + 64] + beta[lane + 64];
        n0 = n0 > 0.f ? n0 : 0.f;
        n1 = n1 > 0.f ? n1 : 0.f;
        out[(size_t)node * GD + lane]      = x[(size_t)node * GD + lane] + n0;
        out[(size_t)node * GD + lane + 64] = x[(size_t)node * GD + lane + 64] + n1;
    }
}

extern "C" void kernel_launch(void* const* d_in, const int* in_sizes, int n_in,
                              void* d_out, int out_size, void* d_ws, size_t ws_size,
                              hipStream_t stream) {
    const float* x       = (const float*)d_in[0];
    const float* W       = (const float*)d_in[2];
    const float* att_src = (const float*)d_in[3];
    const float* att_dst = (const float*)d_in[4];
    const float* bias    = (const float*)d_in[5];
    const float* gamma   = (const float*)d_in[6];
    const float* beta    = (const float*)d_in[7];
    float* out = (float*)d_out;

    char* w = (char*)d_ws;
    unsigned short* xa = (unsigned short*)w; w += (size_t)GN * 144 * 2;
    unsigned short* xb = (unsigned short*)w; w += (size_t)GN * 144 * 2;
    unsigned* cand = (unsigned*)w;           w += (size_t)GN * 48 * 4;
    float2* ew  = (float2*)w; w += (size_t)GN * GK * 8;
    unsigned short* Wth = (unsigned short*)w; w += (size_t)256 * 128 * 2;  // 64 KB
    unsigned short* Wtl = (unsigned short*)w; w += (size_t)256 * 128 * 2;  // 64 KB
    float* uvec = (float*)w; w += (size_t)4 * 128 * 4;                     // 2 KB
    float* sq   = (float*)w; w += (size_t)GN * 4;
    float* a_s  = (float*)w; w += (size_t)GN * GH * 4;
    float* a_d  = (float*)w; w += (size_t)GN * GH * 4;
    int*   fidx = (int*)w;   w += (size_t)GN * GK * 4;
    int*   cnt  = (int*)w;   w += (size_t)GN * 4;      // cnt|curs contiguous
    int*   curs = (int*)w;   w += (size_t)GN * 4;
    int*   offs = (int*)w;   w += (size_t)(GN + 1) * 4;
    int*   elst = (int*)w;   w += (size_t)GN * GK * 4;
    size_t need = (size_t)((char*)w - (char*)d_ws);
    if (ws_size < need) return;   // diagnostic guard

    k_zero<<<(2 * GN + 255) / 256, 256, 0, stream>>>(cnt, 2 * GN);
    k_uvec<<<4, 256, 0, stream>>>(W, att_src, att_dst, uvec);
    k_trans<<<128, 256, 0, stream>>>(W, Wth, Wtl);
    k_conv<<<GN / 4, 256, 0, stream>>>(x, uvec, sq, xa, xb, a_s, a_d);
    k_gemm_topk<<<dim3(64, 8), 256, 0, stream>>>(xa, xb, cand);
    k_refine<<<GN, 256, 0, stream>>>(cand, x, sq, fidx, cnt);
    k_scan<<<1, 256, 0, stream>>>(cnt, offs);
    k_fill<<<GN * GK / 256, 256, 0, stream>>>(fidx, offs, curs, elst, a_s, a_d, ew);
    k_out<<<GN / 16, 256, 0, stream>>>(offs, elst, ew, x, Wth, Wtl, bias, gamma, beta, out);
}

// Round 10
// 221.311 us; speedup vs baseline: 4.1675x; 1.0930x over previous
//
#include <hip/hip_runtime.h>
#include <hip/hip_bf16.h>
#include <math.h>

#define GN 8192
#define GD 128
#define GH 2
#define GK 3
#define NEG_SLOPE 0.2f
#define LN_EPS 1e-5f

using short8  = __attribute__((ext_vector_type(8)))  short;
using float16 = __attribute__((ext_vector_type(16))) float;
using f32x4   = __attribute__((ext_vector_type(4)))  float;

__device__ __forceinline__ float wred(float v) {
    #pragma unroll
    for (int o = 32; o > 0; o >>= 1) v += __shfl_xor(v, o, 64);
    return v;
}
__device__ __forceinline__ float wmax(float v) {
    #pragma unroll
    for (int o = 32; o > 0; o >>= 1) v = fmaxf(v, __shfl_xor(v, o, 64));
    return v;
}

// monotone float->uint encoding (ascending float -> ascending uint, handles negatives)
__device__ __forceinline__ unsigned fenc(float f) {
    unsigned b = __float_as_uint(f);
    return (b & 0x80000000u) ? ~b : (b | 0x80000000u);
}

__device__ __forceinline__ float rawbf2f(unsigned short s) {
    return __uint_as_float(((unsigned)s) << 16);
}
__device__ __forceinline__ unsigned short f2rawbf(float f) {
    __hip_bfloat16 b = __float2bfloat16(f);
    unsigned short r; __builtin_memcpy(&r, &b, 2);
    return r;
}
__device__ __forceinline__ unsigned umin2(unsigned a, unsigned b) { return a < b ? a : b; }
__device__ __forceinline__ unsigned umax2(unsigned a, unsigned b) { return a > b ? a : b; }

__global__ void k_zero(int* p, int n) {
    int t = blockIdx.x * 256 + threadIdx.x;
    if (t < n) p[t] = 0;
}

// u vectors: uvec[b][d] = sum_c W[d][h*128+c] * v[h][c], b = {s0,s1,d0,d1}
__global__ void k_uvec(const float* __restrict__ W, const float* __restrict__ att_src,
                       const float* __restrict__ att_dst, float* __restrict__ uvec) {
    __shared__ float vs[128];
    int b = blockIdx.x, t = threadIdx.x;
    int h = b & 1;
    const float* v = (b < 2 ? att_src : att_dst) + h * 128;
    if (t < 128) vs[t] = v[t];
    __syncthreads();
    int d = t >> 1, half = t & 1;
    const float* wr = W + (size_t)d * 256 + h * 128 + half * 64;
    float s = 0.f;
    for (int c = 0; c < 64; c++) s += wr[c] * vs[half * 64 + c];
    s += __shfl_xor(s, 1, 64);
    if (half == 0) uvec[b * 128 + d] = s;
}

// W transpose into MFMA-B layout: Wt[c][k], k = h*128+d, bf16 hi/lo split
__global__ void k_trans(const float* __restrict__ W,
                        unsigned short* __restrict__ Wth, unsigned short* __restrict__ Wtl) {
    int e = blockIdx.x * 256 + threadIdx.x;   // 32768
    int d = e >> 8, j = e & 255;
    int h = j >> 7, c = j & 127;
    int k = h * 128 + d;
    float w = W[e];
    unsigned short hi = f2rawbf(w);
    Wth[c * 256 + k] = hi;
    Wtl[c * 256 + k] = f2rawbf(w - rawbf2f(hi));
}

// one wave per row: sq, xa=[-2x | hi(sq+512) lo | 0..], xb=[x | 1 1 | 0..],
// plus attention dots a_s/a_d via u-vectors.
__global__ void k_conv(const float* __restrict__ x, const float* __restrict__ uvec,
                       float* __restrict__ sq,
                       unsigned short* __restrict__ xa, unsigned short* __restrict__ xb,
                       float* __restrict__ a_s, float* __restrict__ a_d) {
    int row = blockIdx.x * 4 + (threadIdx.x >> 6);
    int lane = threadIdx.x & 63;
    const float* xr = x + (size_t)row * GD;
    float a0 = xr[lane], a1 = xr[lane + 64];
    float s = wred(a0 * a0 + a1 * a1);
    unsigned short* ar = xa + (size_t)row * 144;
    unsigned short* br = xb + (size_t)row * 144;
    ar[lane] = f2rawbf(-2.f * a0); ar[lane + 64] = f2rawbf(-2.f * a1);
    br[lane] = f2rawbf(a0);        br[lane + 64] = f2rawbf(a1);
    float s0 = wred(a0 * uvec[lane]       + a1 * uvec[64 + lane]);
    float s1 = wred(a0 * uvec[128 + lane] + a1 * uvec[192 + lane]);
    float d0 = wred(a0 * uvec[256 + lane] + a1 * uvec[320 + lane]);
    float d1 = wred(a0 * uvec[384 + lane] + a1 * uvec[448 + lane]);
    if (lane < 16) {
        unsigned short av = 0, bv = 0;
        if (lane == 0)      { av = f2rawbf(s + 512.f); bv = 0x3F80; }
        else if (lane == 1) { float hi = rawbf2f(f2rawbf(s + 512.f));
                              av = f2rawbf(s + 512.f - hi); bv = 0x3F80; }
        ar[128 + lane] = av; br[128 + lane] = bv;
        if (lane == 0) {
            sq[row] = s;
            a_s[row * 2] = s0; a_s[row * 2 + 1] = s1;
            a_d[row * 2] = d0; a_d[row * 2 + 1] = d1;
        }
    }
}

// sorted top-6 of unsigned keys, branchless bubble insert
struct Top6 {
    unsigned a0, a1, a2, a3, a4, a5;
    __device__ __forceinline__ void init() { a0=a1=a2=a3=a4=a5=0xFFFFFFFFu; }
    __device__ __forceinline__ void insert(unsigned k) {
        unsigned m0 = umax2(a0, k);  a0 = umin2(a0, k);
        unsigned m1 = umax2(a1, m0); a1 = umin2(a1, m0);
        unsigned m2 = umax2(a2, m1); a2 = umin2(a2, m1);
        unsigned m3 = umax2(a3, m2); a3 = umin2(a3, m2);
        unsigned m4 = umax2(a4, m3); a4 = umin2(a4, m3);
        a5 = umin2(a5, m4);
    }
};

// MFMA candidate kNN. score'_ij = 512 + sq_i - 2 x_i.x_j (> 0 -> raw bits monotone).
__launch_bounds__(256, 2)
__global__ void k_gemm_topk(const unsigned short* __restrict__ xa,
                            const unsigned short* __restrict__ xb,
                            unsigned* __restrict__ cand) {
    __shared__ unsigned short At[18 * 128 * 8];
    int t = threadIdx.x;
    int w = t >> 6, lane = t & 63, h = lane >> 5, n = lane & 31;
    int col = blockIdx.x * 128 + w * 32 + n;
    int sb = blockIdx.y;

    short8 bfrag[9];
    #pragma unroll
    for (int kc = 0; kc < 9; kc++)
        bfrag[kc] = *(const short8*)(xb + (size_t)col * 144 + (2 * kc + h) * 8);

    Top6 T; T.init();

    for (int it = 0; it < 8; it++) {
        int rowbase = sb * 1024 + it * 128;
        __syncthreads();
        #pragma unroll
        for (int q = t; q < 18 * 128; q += 256) {
            int kb = q >> 7, r = q & 127;
            *(uint4*)&At[(kb * 128 + r) * 8] =
                *(const uint4*)(xa + (size_t)(rowbase + r) * 144 + kb * 8);
        }
        __syncthreads();

        float16 acc[4];
        #pragma unroll
        for (int rs = 0; rs < 4; rs++) acc[rs] = (float16)(0.f);

        #pragma unroll
        for (int kc = 0; kc < 9; kc++) {
            short8 a[4];
            #pragma unroll
            for (int rs = 0; rs < 4; rs++)
                a[rs] = *(const short8*)&At[((2 * kc + h) * 128 + rs * 32 + n) * 8];
            #pragma unroll
            for (int rs = 0; rs < 4; rs++)
                acc[rs] = __builtin_amdgcn_mfma_f32_32x32x16_bf16(a[rs], bfrag[kc], acc[rs], 0, 0, 0);
        }

        #pragma unroll
        for (int rs = 0; rs < 4; rs++) {
            float16 A = acc[rs];
            int rb = rowbase + 4 * h + rs * 32;
            unsigned kk[16];
            #pragma unroll
            for (int r = 0; r < 16; r++)
                kk[r] = (__float_as_uint(A[r]) & 0xFFFFE000u) |
                        (unsigned)(rb + (r & 3) + 8 * (r >> 2));
            unsigned ma = umin2(umin2(umin2(kk[0],kk[1]),umin2(kk[2],kk[3])),
                                umin2(umin2(kk[4],kk[5]),umin2(kk[6],kk[7])));
            unsigned mb = umin2(umin2(umin2(kk[8],kk[9]),umin2(kk[10],kk[11])),
                                umin2(umin2(kk[12],kk[13]),umin2(kk[14],kk[15])));
            if (umin2(ma, mb) <= T.a5) {
                #pragma unroll
                for (int r = 0; r < 16; r++) T.insert(kk[r]);
            }
        }
    }

    unsigned p0 = (unsigned)__shfl_xor((int)T.a0, 32), p1 = (unsigned)__shfl_xor((int)T.a1, 32),
             p2 = (unsigned)__shfl_xor((int)T.a2, 32), p3 = (unsigned)__shfl_xor((int)T.a3, 32),
             p4 = (unsigned)__shfl_xor((int)T.a4, 32), p5 = (unsigned)__shfl_xor((int)T.a5, 32);
    T.insert(p0); T.insert(p1); T.insert(p2); T.insert(p3); T.insert(p4); T.insert(p5);

    if (h == 0) {
        unsigned* c0 = cand + (size_t)col * 48 + sb * 6;
        c0[0]=T.a0; c0[1]=T.a1; c0[2]=T.a2; c0[3]=T.a3; c0[4]=T.a4; c0[5]=T.a5;
    }
}

__device__ __forceinline__ int clampN(int v) {
    return v < 0 ? 0 : (v >= GN ? GN - 1 : v);
}

// exact fp32 refine + degree count. One wave per node; lane c owns candidate c.
// Top-3 via 3 rounds of branchless 64-lane min on packed key fenc(d2)::idx
// (lexicographic (d2, idx) — matches lax.top_k tie-break; idx unique per node).
__global__ void k_refine(const unsigned* __restrict__ cand,
                         const float* __restrict__ x, const float* __restrict__ sq,
                         int* __restrict__ fidx, int* __restrict__ cnt) {
    __shared__ float xjs[4][132];
    int t = threadIdx.x, wv = t >> 6, lane = t & 63;
    int j = blockIdx.x * 4 + wv;
    xjs[wv][lane] = x[(size_t)j * GD + lane];
    xjs[wv][64 + lane] = x[(size_t)j * GD + 64 + lane];
    // same-wave LDS RAW: compiler inserts lgkmcnt wait; no barrier needed.
    float sqj = sq[j];
    unsigned long long key = ~0ull;
    if (lane < 48) {
        int idx = (int)(cand[(size_t)j * 48 + lane] & 8191u);
        const float* xi = x + (size_t)idx * GD;
        float p = 0.f;
        #pragma unroll
        for (int d4 = 0; d4 < 32; d4++) {
            float4 a = *(const float4*)(xi + d4 * 4);
            float4 b = *(const float4*)&xjs[wv][d4 * 4];   // broadcast ds_read_b128
            p += a.x * b.x + a.y * b.y + a.z * b.z + a.w * b.w;
        }
        float d2 = sqj + sq[idx] - 2.f * p;
        key = ((unsigned long long)fenc(d2) << 32) | (unsigned)idx;
    }
    int out3[3];
    #pragma unroll
    for (int r = 0; r < 3; r++) {
        unsigned long long k = key;
        #pragma unroll
        for (int o = 32; o > 0; o >>= 1) {
            unsigned long long other = __shfl_xor(k, o, 64);
            k = k < other ? k : other;
        }
        out3[r] = (int)(unsigned)(k & 0xffffffffu);
        key = (key == k) ? ~0ull : key;   // remove selected (keys unique)
    }
    if (lane == 0) {
        int i0 = clampN(out3[0]), i1 = clampN(out3[1]), i2 = clampN(out3[2]);
        fidx[j * 3 + 0] = i0; fidx[j * 3 + 1] = i1; fidx[j * 3 + 2] = i2;
        atomicAdd(&cnt[i0], 1); atomicAdd(&cnt[i1], 1); atomicAdd(&cnt[i2], 1);
    }
}

__global__ void k_scan(const int* __restrict__ cnt, int* __restrict__ offs) {
    __shared__ int part[256];
    int t = threadIdx.x;
    int base = t * 32;
    int loc[32];
    int s = 0;
    #pragma unroll
    for (int k = 0; k < 32; k++) { loc[k] = s; s += cnt[base + k]; }
    part[t] = s;
    __syncthreads();
    if (t == 0) {
        int run = 0;
        for (int k = 0; k < 256; k++) { int v = part[k]; part[k] = run; run += v; }
        offs[GN] = run;
    }
    __syncthreads();
    int b = part[t];
    #pragma unroll
    for (int k = 0; k < 32; k++) offs[base + k] = b + loc[k];
}

// edge-parallel fill: CSR scatter + per-edge leaky-relu'd logits ew[slot]
__global__ void k_fill(const int* __restrict__ fidx, const int* __restrict__ offs,
                       int* __restrict__ cursor, int* __restrict__ elist,
                       const float* __restrict__ a_s, const float* __restrict__ a_d,
                       float2* __restrict__ ew) {
    int eid = blockIdx.x * 256 + threadIdx.x;
    int i = clampN(fidx[eid]);
    int src = eid / 3;
    float2 as = ((const float2*)a_s)[src];
    float2 ad = ((const float2*)a_d)[i];
    float e0 = as.x + ad.x; e0 = e0 >= 0.f ? e0 : NEG_SLOPE * e0;
    float e1 = as.y + ad.y; e1 = e1 >= 0.f ? e1 : NEG_SLOPE * e1;
    int pos = atomicAdd(&cursor[i], 1);
    int slot = offs[i] + pos;
    if (slot < GN * GK) { elist[slot] = src; ew[slot] = make_float2(e0, e1); }
}

// fused: in-wave softmax stats + z-accumulate -> MFMA GEMM y = z@Wt (err-compensated
// bf16 hi/lo) -> bias + LN + ReLU + residual.
__launch_bounds__(256, 2)
__global__ void k_out(const int* __restrict__ offs, const int* __restrict__ elst,
                      const float2* __restrict__ ew,
                      const float* __restrict__ x,
                      const unsigned short* __restrict__ Wth,
                      const unsigned short* __restrict__ Wtl,
                      const float* __restrict__ bias, const float* __restrict__ gamma,
                      const float* __restrict__ beta, float* __restrict__ out) {
    __shared__ unsigned short zh[16][264];
    __shared__ unsigned short zl[16][264];
    __shared__ float os[16][132];
    int t = threadIdx.x, i0 = blockIdx.x * 16;
    int wv = t >> 6, lane = t & 63;

    #pragma unroll
    for (int pp = 0; pp < 4; pp++) {
        int r = wv * 4 + pp, node = i0 + r;
        int s = offs[node], e = offs[node + 1];
        float m0 = -1e30f, m1 = -1e30f;
        for (int k = s + lane; k < e; k += 64) {
            float2 v = ew[k];
            m0 = fmaxf(m0, v.x); m1 = fmaxf(m1, v.y);
        }
        m0 = wmax(m0); m1 = wmax(m1);
        float s0 = 0.f, s1 = 0.f;
        for (int k = s + lane; k < e; k += 64) {
            float2 v = ew[k];
            s0 += expf(v.x - m0); s1 += expf(v.y - m1);
        }
        s0 = wred(s0); s1 = wred(s1);
        float dn0 = 0.5f / s0, dn1 = 0.5f / s1;

        float z00 = 0.f, z01 = 0.f, z10 = 0.f, z11 = 0.f;
        for (int k = s; k < e; k++) {
            int j = elst[k];
            float2 v = ew[k];
            float w0 = expf(v.x - m0), w1 = expf(v.y - m1);
            float xv0 = x[(size_t)j * GD + lane];
            float xv1 = x[(size_t)j * GD + 64 + lane];
            z00 += w0 * xv0; z01 += w0 * xv1;
            z10 += w1 * xv0; z11 += w1 * xv1;
        }
        float v0 = z00 * dn0, v1 = z01 * dn0, v2 = z10 * dn1, v3 = z11 * dn1;
        unsigned short h0 = f2rawbf(v0), h1 = f2rawbf(v1), h2 = f2rawbf(v2), h3 = f2rawbf(v3);
        zh[r][lane]       = h0; zl[r][lane]       = f2rawbf(v0 - rawbf2f(h0));
        zh[r][64 + lane]  = h1; zl[r][64 + lane]  = f2rawbf(v1 - rawbf2f(h1));
        zh[r][128 + lane] = h2; zl[r][128 + lane] = f2rawbf(v2 - rawbf2f(h2));
        zh[r][192 + lane] = h3; zl[r][192 + lane] = f2rawbf(v3 - rawbf2f(h3));
    }
    __syncthreads();

    {
        int qd = lane >> 4, an = lane & 15;
        int c0 = wv * 32 + an, c1 = wv * 32 + 16 + an;
        f32x4 acc0 = {0.f, 0.f, 0.f, 0.f}, acc1 = {0.f, 0.f, 0.f, 0.f};
        #pragma unroll
        for (int s = 0; s < 8; s++) {
            int ko = s * 32 + qd * 8;
            short8 ah = *(const short8*)&zh[an][ko];
            short8 al = *(const short8*)&zl[an][ko];
            short8 bh0 = *(const short8*)(Wth + (size_t)c0 * 256 + ko);
            short8 bl0 = *(const short8*)(Wtl + (size_t)c0 * 256 + ko);
            short8 bh1 = *(const short8*)(Wth + (size_t)c1 * 256 + ko);
            short8 bl1 = *(const short8*)(Wtl + (size_t)c1 * 256 + ko);
            acc0 = __builtin_amdgcn_mfma_f32_16x16x32_bf16(ah, bh0, acc0, 0, 0, 0);
            acc0 = __builtin_amdgcn_mfma_f32_16x16x32_bf16(al, bh0, acc0, 0, 0, 0);
            acc0 = __builtin_amdgcn_mfma_f32_16x16x32_bf16(ah, bl0, acc0, 0, 0, 0);
            acc1 = __builtin_amdgcn_mfma_f32_16x16x32_bf16(ah, bh1, acc1, 0, 0, 0);
            acc1 = __builtin_amdgcn_mfma_f32_16x16x32_bf16(al, bh1, acc1, 0, 0, 0);
            acc1 = __builtin_amdgcn_mfma_f32_16x16x32_bf16(ah, bl1, acc1, 0, 0, 0);
        }
        #pragma unroll
        for (int r = 0; r < 4; r++) {
            os[qd * 4 + r][c0] = acc0[r];
            os[qd * 4 + r][c1] = acc1[r];
        }
    }
    __syncthreads();

    #pragma unroll
    for (int pp = 0; pp < 4; pp++) {
        int r = wv * 4 + pp, node = i0 + r;
        float y0 = os[r][lane] + bias[lane];
        float y1 = os[r][lane + 64] + bias[lane + 64];
        float mu = wred(y0 + y1) * (1.f / 128.f);
        float c0 = y0 - mu, c1 = y1 - mu;
        float var = wred(c0 * c0 + c1 * c1) * (1.f / 128.f);
        float rs2 = 1.f / sqrtf(var + LN_EPS);
        float n0 = c0 * rs2 * gamma[lane] + beta[lane];
        float n1 = c1 * rs2 * gamma[lane + 64] + beta[lane + 64];
        n0 = n0 > 0.f ? n0 : 0.f;
        n1 = n1 > 0.f ? n1 : 0.f;
        out[(size_t)node * GD + lane]      = x[(size_t)node * GD + lane] + n0;
        out[(size_t)node * GD + lane + 64] = x[(size_t)node * GD + lane + 64] + n1;
    }
}

extern "C" void kernel_launch(void* const* d_in, const int* in_sizes, int n_in,
                              void* d_out, int out_size, void* d_ws, size_t ws_size,
                              hipStream_t stream) {
    const float* x       = (const float*)d_in[0];
    const float* W       = (const float*)d_in[2];
    const float* att_src = (const float*)d_in[3];
    const float* att_dst = (const float*)d_in[4];
    const float* bias    = (const float*)d_in[5];
    const float* gamma   = (const float*)d_in[6];
    const float* beta    = (const float*)d_in[7];
    float* out = (float*)d_out;

    char* w = (char*)d_ws;
    unsigned short* xa = (unsigned short*)w; w += (size_t)GN * 144 * 2;
    unsigned short* xb = (unsigned short*)w; w += (size_t)GN * 144 * 2;
    unsigned* cand = (unsigned*)w;           w += (size_t)GN * 48 * 4;
    float2* ew  = (float2*)w; w += (size_t)GN * GK * 8;
    unsigned short* Wth = (unsigned short*)w; w += (size_t)256 * 128 * 2;
    unsigned short* Wtl = (unsigned short*)w; w += (size_t)256 * 128 * 2;
    float* uvec = (float*)w; w += (size_t)4 * 128 * 4;
    float* sq   = (float*)w; w += (size_t)GN * 4;
    float* a_s  = (float*)w; w += (size_t)GN * GH * 4;
    float* a_d  = (float*)w; w += (size_t)GN * GH * 4;
    int*   fidx = (int*)w;   w += (size_t)GN * GK * 4;
    int*   cnt  = (int*)w;   w += (size_t)GN * 4;      // cnt|curs contiguous
    int*   curs = (int*)w;   w += (size_t)GN * 4;
    int*   offs = (int*)w;   w += (size_t)(GN + 1) * 4;
    int*   elst = (int*)w;   w += (size_t)GN * GK * 4;
    size_t need = (size_t)((char*)w - (char*)d_ws);
    if (ws_size < need) return;   // diagnostic guard

    k_zero<<<(2 * GN + 255) / 256, 256, 0, stream>>>(cnt, 2 * GN);
    k_uvec<<<4, 256, 0, stream>>>(W, att_src, att_dst, uvec);
    k_trans<<<128, 256, 0, stream>>>(W, Wth, Wtl);
    k_conv<<<GN / 4, 256, 0, stream>>>(x, uvec, sq, xa, xb, a_s, a_d);
    k_gemm_topk<<<dim3(64, 8), 256, 0, stream>>>(xa, xb, cand);
    k_refine<<<GN / 4, 256, 0, stream>>>(cand, x, sq, fidx, cnt);
    k_scan<<<1, 256, 0, stream>>>(cnt, offs);
    k_fill<<<GN * GK / 256, 256, 0, stream>>>(fidx, offs, curs, elst, a_s, a_d, ew);
    k_out<<<GN / 16, 256, 0, stream>>>(offs, elst, ew, x, Wth, Wtl, bias, gamma, beta, out);
}

// Round 11
// 217.862 us; speedup vs baseline: 4.2335x; 1.0158x over previous
//
#include <hip/hip_runtime.h>
#include <hip/hip_bf16.h>
#include <math.h>

#define GN 8192
#define GD 128
#define GH 2
#define GK 3
#define NEG_SLOPE 0.2f
#define LN_EPS 1e-5f

using short8  = __attribute__((ext_vector_type(8)))  short;
using float16 = __attribute__((ext_vector_type(16))) float;
using f32x4   = __attribute__((ext_vector_type(4)))  float;

__device__ __forceinline__ float wred(float v) {
    #pragma unroll
    for (int o = 32; o > 0; o >>= 1) v += __shfl_xor(v, o, 64);
    return v;
}
__device__ __forceinline__ float wmax(float v) {
    #pragma unroll
    for (int o = 32; o > 0; o >>= 1) v = fmaxf(v, __shfl_xor(v, o, 64));
    return v;
}

// monotone float->uint encoding (ascending float -> ascending uint)
__device__ __forceinline__ unsigned fenc(float f) {
    unsigned b = __float_as_uint(f);
    return (b & 0x80000000u) ? ~b : (b | 0x80000000u);
}

__device__ __forceinline__ float rawbf2f(unsigned short s) {
    return __uint_as_float(((unsigned)s) << 16);
}
__device__ __forceinline__ unsigned short f2rawbf(float f) {
    __hip_bfloat16 b = __float2bfloat16(f);
    unsigned short r; __builtin_memcpy(&r, &b, 2);
    return r;
}
__device__ __forceinline__ unsigned umin2(unsigned a, unsigned b) { return a < b ? a : b; }
__device__ __forceinline__ unsigned umax2(unsigned a, unsigned b) { return a > b ? a : b; }

__global__ void k_zero(int* p, int n) {
    int t = blockIdx.x * 256 + threadIdx.x;
    if (t < n) p[t] = 0;
}

// u vectors: uvec[b][d] = sum_c W[d][h*128+c] * v[h][c], b = {s0,s1,d0,d1}
__global__ void k_uvec(const float* __restrict__ W, const float* __restrict__ att_src,
                       const float* __restrict__ att_dst, float* __restrict__ uvec) {
    __shared__ float vs[128];
    int b = blockIdx.x, t = threadIdx.x;
    int h = b & 1;
    const float* v = (b < 2 ? att_src : att_dst) + h * 128;
    if (t < 128) vs[t] = v[t];
    __syncthreads();
    int d = t >> 1, half = t & 1;
    const float* wr = W + (size_t)d * 256 + h * 128 + half * 64;
    float s = 0.f;
    for (int c = 0; c < 64; c++) s += wr[c] * vs[half * 64 + c];
    s += __shfl_xor(s, 1, 64);
    if (half == 0) uvec[b * 128 + d] = s;
}

// W transpose into MFMA-B layout: Wt[c][k], k = h*128+d, bf16 hi/lo split
__global__ void k_trans(const float* __restrict__ W,
                        unsigned short* __restrict__ Wth, unsigned short* __restrict__ Wtl) {
    int e = blockIdx.x * 256 + threadIdx.x;   // 32768
    int d = e >> 8, j = e & 255;
    int h = j >> 7, c = j & 127;
    int k = h * 128 + d;
    float w = W[e];
    unsigned short hi = f2rawbf(w);
    Wth[c * 256 + k] = hi;
    Wtl[c * 256 + k] = f2rawbf(w - rawbf2f(hi));
}

// one wave per row: sq, xa=[-2x | hi(sq+512) lo | 0..], xb=[x | 1 1 | 0..],
// plus attention dots a_s/a_d via u-vectors.
__global__ void k_conv(const float* __restrict__ x, const float* __restrict__ uvec,
                       float* __restrict__ sq,
                       unsigned short* __restrict__ xa, unsigned short* __restrict__ xb,
                       float* __restrict__ a_s, float* __restrict__ a_d) {
    int row = blockIdx.x * 4 + (threadIdx.x >> 6);
    int lane = threadIdx.x & 63;
    const float* xr = x + (size_t)row * GD;
    float a0 = xr[lane], a1 = xr[lane + 64];
    float s = wred(a0 * a0 + a1 * a1);
    unsigned short* ar = xa + (size_t)row * 144;
    unsigned short* br = xb + (size_t)row * 144;
    ar[lane] = f2rawbf(-2.f * a0); ar[lane + 64] = f2rawbf(-2.f * a1);
    br[lane] = f2rawbf(a0);        br[lane + 64] = f2rawbf(a1);
    float s0 = wred(a0 * uvec[lane]       + a1 * uvec[64 + lane]);
    float s1 = wred(a0 * uvec[128 + lane] + a1 * uvec[192 + lane]);
    float d0 = wred(a0 * uvec[256 + lane] + a1 * uvec[320 + lane]);
    float d1 = wred(a0 * uvec[384 + lane] + a1 * uvec[448 + lane]);
    if (lane < 16) {
        unsigned short av = 0, bv = 0;
        if (lane == 0)      { av = f2rawbf(s + 512.f); bv = 0x3F80; }
        else if (lane == 1) { float hi = rawbf2f(f2rawbf(s + 512.f));
                              av = f2rawbf(s + 512.f - hi); bv = 0x3F80; }
        ar[128 + lane] = av; br[128 + lane] = bv;
        if (lane == 0) {
            sq[row] = s;
            a_s[row * 2] = s0; a_s[row * 2 + 1] = s1;
            a_d[row * 2] = d0; a_d[row * 2 + 1] = d1;
        }
    }
}

// sorted top-6 of unsigned keys, branchless bubble insert
struct Top6 {
    unsigned a0, a1, a2, a3, a4, a5;
    __device__ __forceinline__ void init() { a0=a1=a2=a3=a4=a5=0xFFFFFFFFu; }
    __device__ __forceinline__ void insert(unsigned k) {
        unsigned m0 = umax2(a0, k);  a0 = umin2(a0, k);
        unsigned m1 = umax2(a1, m0); a1 = umin2(a1, m0);
        unsigned m2 = umax2(a2, m1); a2 = umin2(a2, m1);
        unsigned m3 = umax2(a3, m2); a3 = umin2(a3, m2);
        unsigned m4 = umax2(a4, m3); a4 = umin2(a4, m3);
        a5 = umin2(a5, m4);
    }
};

// MFMA candidate kNN. score'_ij = 512 + sq_i - 2 x_i.x_j (> 0 -> raw bits monotone).
__launch_bounds__(256, 2)
__global__ void k_gemm_topk(const unsigned short* __restrict__ xa,
                            const unsigned short* __restrict__ xb,
                            unsigned* __restrict__ cand) {
    __shared__ unsigned short At[18 * 128 * 8];
    int t = threadIdx.x;
    int w = t >> 6, lane = t & 63, h = lane >> 5, n = lane & 31;
    int col = blockIdx.x * 128 + w * 32 + n;
    int sb = blockIdx.y;

    short8 bfrag[9];
    #pragma unroll
    for (int kc = 0; kc < 9; kc++)
        bfrag[kc] = *(const short8*)(xb + (size_t)col * 144 + (2 * kc + h) * 8);

    Top6 T; T.init();

    for (int it = 0; it < 8; it++) {
        int rowbase = sb * 1024 + it * 128;
        __syncthreads();
        #pragma unroll
        for (int q = t; q < 18 * 128; q += 256) {
            int kb = q >> 7, r = q & 127;
            *(uint4*)&At[(kb * 128 + r) * 8] =
                *(const uint4*)(xa + (size_t)(rowbase + r) * 144 + kb * 8);
        }
        __syncthreads();

        float16 acc[4];
        #pragma unroll
        for (int rs = 0; rs < 4; rs++) acc[rs] = (float16)(0.f);

        #pragma unroll
        for (int kc = 0; kc < 9; kc++) {
            short8 a[4];
            #pragma unroll
            for (int rs = 0; rs < 4; rs++)
                a[rs] = *(const short8*)&At[((2 * kc + h) * 128 + rs * 32 + n) * 8];
            #pragma unroll
            for (int rs = 0; rs < 4; rs++)
                acc[rs] = __builtin_amdgcn_mfma_f32_32x32x16_bf16(a[rs], bfrag[kc], acc[rs], 0, 0, 0);
        }

        #pragma unroll
        for (int rs = 0; rs < 4; rs++) {
            float16 A = acc[rs];
            int rb = rowbase + 4 * h + rs * 32;
            unsigned kk[16];
            #pragma unroll
            for (int r = 0; r < 16; r++)
                kk[r] = (__float_as_uint(A[r]) & 0xFFFFE000u) |
                        (unsigned)(rb + (r & 3) + 8 * (r >> 2));
            unsigned ma = umin2(umin2(umin2(kk[0],kk[1]),umin2(kk[2],kk[3])),
                                umin2(umin2(kk[4],kk[5]),umin2(kk[6],kk[7])));
            unsigned mb = umin2(umin2(umin2(kk[8],kk[9]),umin2(kk[10],kk[11])),
                                umin2(umin2(kk[12],kk[13]),umin2(kk[14],kk[15])));
            if (umin2(ma, mb) <= T.a5) {
                #pragma unroll
                for (int r = 0; r < 16; r++) T.insert(kk[r]);
            }
        }
    }

    unsigned p0 = (unsigned)__shfl_xor((int)T.a0, 32), p1 = (unsigned)__shfl_xor((int)T.a1, 32),
             p2 = (unsigned)__shfl_xor((int)T.a2, 32), p3 = (unsigned)__shfl_xor((int)T.a3, 32),
             p4 = (unsigned)__shfl_xor((int)T.a4, 32), p5 = (unsigned)__shfl_xor((int)T.a5, 32);
    T.insert(p0); T.insert(p1); T.insert(p2); T.insert(p3); T.insert(p4); T.insert(p5);

    if (h == 0) {
        unsigned* c0 = cand + (size_t)col * 48 + sb * 6;
        c0[0]=T.a0; c0[1]=T.a1; c0[2]=T.a2; c0[3]=T.a3; c0[4]=T.a4; c0[5]=T.a5;
    }
}

__device__ __forceinline__ int clampN(int v) {
    return v < 0 ? 0 : (v >= GN ? GN - 1 : v);
}

// exact fp32 refine + degree count. One wave per node; lane c owns candidate c.
__global__ void k_refine(const unsigned* __restrict__ cand,
                         const float* __restrict__ x, const float* __restrict__ sq,
                         int* __restrict__ fidx, int* __restrict__ cnt) {
    __shared__ float xjs[4][132];
    int t = threadIdx.x, wv = t >> 6, lane = t & 63;
    int j = blockIdx.x * 4 + wv;
    xjs[wv][lane] = x[(size_t)j * GD + lane];
    xjs[wv][64 + lane] = x[(size_t)j * GD + 64 + lane];
    float sqj = sq[j];
    unsigned long long key = ~0ull;
    if (lane < 48) {
        int idx = (int)(cand[(size_t)j * 48 + lane] & 8191u);
        const float* xi = x + (size_t)idx * GD;
        float p = 0.f;
        #pragma unroll
        for (int d4 = 0; d4 < 32; d4++) {
            float4 a = *(const float4*)(xi + d4 * 4);
            float4 b = *(const float4*)&xjs[wv][d4 * 4];
            p += a.x * b.x + a.y * b.y + a.z * b.z + a.w * b.w;
        }
        float d2 = sqj + sq[idx] - 2.f * p;
        key = ((unsigned long long)fenc(d2) << 32) | (unsigned)idx;
    }
    int out3[3];
    #pragma unroll
    for (int r = 0; r < 3; r++) {
        unsigned long long k = key;
        #pragma unroll
        for (int o = 32; o > 0; o >>= 1) {
            unsigned long long other = __shfl_xor(k, o, 64);
            k = k < other ? k : other;
        }
        out3[r] = (int)(unsigned)(k & 0xffffffffu);
        key = (key == k) ? ~0ull : key;
    }
    if (lane == 0) {
        int i0 = clampN(out3[0]), i1 = clampN(out3[1]), i2 = clampN(out3[2]);
        fidx[j * 3 + 0] = i0; fidx[j * 3 + 1] = i1; fidx[j * 3 + 2] = i2;
        atomicAdd(&cnt[i0], 1); atomicAdd(&cnt[i1], 1); atomicAdd(&cnt[i2], 1);
    }
}

__global__ void k_scan(const int* __restrict__ cnt, int* __restrict__ offs) {
    __shared__ int part[256];
    int t = threadIdx.x;
    int base = t * 32;
    int loc[32];
    int s = 0;
    #pragma unroll
    for (int k = 0; k < 32; k++) { loc[k] = s; s += cnt[base + k]; }
    part[t] = s;
    __syncthreads();
    if (t == 0) {
        int run = 0;
        for (int k = 0; k < 256; k++) { int v = part[k]; part[k] = run; run += v; }
        offs[GN] = run;
    }
    __syncthreads();
    int b = part[t];
    #pragma unroll
    for (int k = 0; k < 32; k++) offs[base + k] = b + loc[k];
}

// edge-parallel fill: CSR scatter + per-edge leaky-relu'd logits ew[slot]
__global__ void k_fill(const int* __restrict__ fidx, const int* __restrict__ offs,
                       int* __restrict__ cursor, int* __restrict__ elist,
                       const float* __restrict__ a_s, const float* __restrict__ a_d,
                       float2* __restrict__ ew) {
    int eid = blockIdx.x * 256 + threadIdx.x;
    int i = clampN(fidx[eid]);
    int src = eid / 3;
    float2 as = ((const float2*)a_s)[src];
    float2 ad = ((const float2*)a_d)[i];
    float e0 = as.x + ad.x; e0 = e0 >= 0.f ? e0 : NEG_SLOPE * e0;
    float e1 = as.y + ad.y; e1 = e1 >= 0.f ? e1 : NEG_SLOPE * e1;
    int pos = atomicAdd(&cursor[i], 1);
    int slot = offs[i] + pos;
    if (slot < GN * GK) { elist[slot] = src; ew[slot] = make_float2(e0, e1); }
}

// fused aggregation: 16 nodes/block, 512 threads (8 waves; 2 nodes/wave).
// phase A: in-wave softmax stats + combined predicated z-loop (pipelinable).
// phase B: MFMA GEMM y = z@Wt (err-compensated bf16 hi/lo).
// phase C: bias + LN + ReLU + residual.
__launch_bounds__(512, 4)
__global__ void k_out(const int* __restrict__ offs, const int* __restrict__ elst,
                      const float2* __restrict__ ew,
                      const float* __restrict__ x,
                      const unsigned short* __restrict__ Wth,
                      const unsigned short* __restrict__ Wtl,
                      const float* __restrict__ bias, const float* __restrict__ gamma,
                      const float* __restrict__ beta, float* __restrict__ out) {
    __shared__ unsigned short zh[16][264];
    __shared__ unsigned short zl[16][264];
    __shared__ float os[16][132];
    int t = threadIdx.x, i0 = blockIdx.x * 16;
    int wv = t >> 6, lane = t & 63;   // wv 0..7

    // phase A: wave handles nodes nA = i0+wv*2, nB = nA+1 (adjacent CSR ranges)
    {
        int nA = i0 + wv * 2;
        int b0 = offs[nA], b1 = offs[nA + 1], b2 = offs[nA + 2];

        float mA0 = -1e30f, mA1 = -1e30f, mB0 = -1e30f, mB1 = -1e30f;
        for (int k = b0 + lane; k < b1; k += 64) {
            float2 v = ew[k]; mA0 = fmaxf(mA0, v.x); mA1 = fmaxf(mA1, v.y);
        }
        for (int k = b1 + lane; k < b2; k += 64) {
            float2 v = ew[k]; mB0 = fmaxf(mB0, v.x); mB1 = fmaxf(mB1, v.y);
        }
        mA0 = wmax(mA0); mA1 = wmax(mA1); mB0 = wmax(mB0); mB1 = wmax(mB1);
        float sA0 = 0.f, sA1 = 0.f, sB0 = 0.f, sB1 = 0.f;
        for (int k = b0 + lane; k < b1; k += 64) {
            float2 v = ew[k]; sA0 += expf(v.x - mA0); sA1 += expf(v.y - mA1);
        }
        for (int k = b1 + lane; k < b2; k += 64) {
            float2 v = ew[k]; sB0 += expf(v.x - mB0); sB1 += expf(v.y - mB1);
        }
        sA0 = wred(sA0); sA1 = wred(sA1); sB0 = wred(sB0); sB1 = wred(sB1);
        float dA0 = 0.5f / sA0, dA1 = 0.5f / sA1, dB0 = 0.5f / sB0, dB1 = 0.5f / sB1;

        // combined z loop: single dynamic loop over [b0,b2) with branchless node select
        float zA00 = 0.f, zA01 = 0.f, zA10 = 0.f, zA11 = 0.f;
        float zB00 = 0.f, zB01 = 0.f, zB10 = 0.f, zB11 = 0.f;
        for (int k = b0; k < b2; k++) {
            int j = elst[k];
            float2 v = ew[k];
            bool inB = k >= b1;
            float mh0 = inB ? mB0 : mA0, mh1 = inB ? mB1 : mA1;
            float w0 = expf(v.x - mh0), w1 = expf(v.y - mh1);
            float w0A = inB ? 0.f : w0, w0B = inB ? w0 : 0.f;
            float w1A = inB ? 0.f : w1, w1B = inB ? w1 : 0.f;
            const float* xr = x + (size_t)j * GD;
            float xv0 = xr[lane], xv1 = xr[64 + lane];
            zA00 += w0A * xv0; zA01 += w0A * xv1;
            zA10 += w1A * xv0; zA11 += w1A * xv1;
            zB00 += w0B * xv0; zB01 += w0B * xv1;
            zB10 += w1B * xv0; zB11 += w1B * xv1;
        }
        int rA = wv * 2, rB = rA + 1;
        float v0 = zA00 * dA0, v1 = zA01 * dA0, v2 = zA10 * dA1, v3 = zA11 * dA1;
        unsigned short h0 = f2rawbf(v0), h1 = f2rawbf(v1), h2 = f2rawbf(v2), h3 = f2rawbf(v3);
        zh[rA][lane]       = h0; zl[rA][lane]       = f2rawbf(v0 - rawbf2f(h0));
        zh[rA][64 + lane]  = h1; zl[rA][64 + lane]  = f2rawbf(v1 - rawbf2f(h1));
        zh[rA][128 + lane] = h2; zl[rA][128 + lane] = f2rawbf(v2 - rawbf2f(h2));
        zh[rA][192 + lane] = h3; zl[rA][192 + lane] = f2rawbf(v3 - rawbf2f(h3));
        v0 = zB00 * dB0; v1 = zB01 * dB0; v2 = zB10 * dB1; v3 = zB11 * dB1;
        h0 = f2rawbf(v0); h1 = f2rawbf(v1); h2 = f2rawbf(v2); h3 = f2rawbf(v3);
        zh[rB][lane]       = h0; zl[rB][lane]       = f2rawbf(v0 - rawbf2f(h0));
        zh[rB][64 + lane]  = h1; zl[rB][64 + lane]  = f2rawbf(v1 - rawbf2f(h1));
        zh[rB][128 + lane] = h2; zl[rB][128 + lane] = f2rawbf(v2 - rawbf2f(h2));
        zh[rB][192 + lane] = h3; zl[rB][192 + lane] = f2rawbf(v3 - rawbf2f(h3));
    }
    __syncthreads();

    // phase B: y[16][128] = z[16][256] @ Wt[256][128]; wave wv owns 16-col group
    {
        int qd = lane >> 4, an = lane & 15;
        int c = wv * 16 + an;
        f32x4 acc = {0.f, 0.f, 0.f, 0.f};
        #pragma unroll
        for (int s = 0; s < 8; s++) {
            int ko = s * 32 + qd * 8;
            short8 ah = *(const short8*)&zh[an][ko];
            short8 al = *(const short8*)&zl[an][ko];
            short8 bh = *(const short8*)(Wth + (size_t)c * 256 + ko);
            short8 bl = *(const short8*)(Wtl + (size_t)c * 256 + ko);
            acc = __builtin_amdgcn_mfma_f32_16x16x32_bf16(ah, bh, acc, 0, 0, 0);
            acc = __builtin_amdgcn_mfma_f32_16x16x32_bf16(al, bh, acc, 0, 0, 0);
            acc = __builtin_amdgcn_mfma_f32_16x16x32_bf16(ah, bl, acc, 0, 0, 0);
        }
        #pragma unroll
        for (int r = 0; r < 4; r++) os[qd * 4 + r][c] = acc[r];
    }
    __syncthreads();

    // phase C: bias + LN + ReLU + residual (2 nodes per wave)
    #pragma unroll
    for (int pp = 0; pp < 2; pp++) {
        int r = wv * 2 + pp, node = i0 + r;
        float y0 = os[r][lane] + bias[lane];
        float y1 = os[r][lane + 64] + bias[lane + 64];
        float mu = wred(y0 + y1) * (1.f / 128.f);
        float c0 = y0 - mu, c1 = y1 - mu;
        float var = wred(c0 * c0 + c1 * c1) * (1.f / 128.f);
        float rs2 = 1.f / sqrtf(var + LN_EPS);
        float n0 = c0 * rs2 * gamma[lane] + beta[lane];
        float n1 = c1 * rs2 * gamma[lane + 64] + beta[lane + 64];
        n0 = n0 > 0.f ? n0 : 0.f;
        n1 = n1 > 0.f ? n1 : 0.f;
        out[(size_t)node * GD + lane]      = x[(size_t)node * GD + lane] + n0;
        out[(size_t)node * GD + lane + 64] = x[(size_t)node * GD + lane + 64] + n1;
    }
}

extern "C" void kernel_launch(void* const* d_in, const int* in_sizes, int n_in,
                              void* d_out, int out_size, void* d_ws, size_t ws_size,
                              hipStream_t stream) {
    const float* x       = (const float*)d_in[0];
    const float* W       = (const float*)d_in[2];
    const float* att_src = (const float*)d_in[3];
    const float* att_dst = (const float*)d_in[4];
    const float* bias    = (const float*)d_in[5];
    const float* gamma   = (const float*)d_in[6];
    const float* beta    = (const float*)d_in[7];
    float* out = (float*)d_out;

    char* w = (char*)d_ws;
    unsigned short* xa = (unsigned short*)w; w += (size_t)GN * 144 * 2;
    unsigned short* xb = (unsigned short*)w; w += (size_t)GN * 144 * 2;
    unsigned* cand = (unsigned*)w;           w += (size_t)GN * 48 * 4;
    float2* ew  = (float2*)w; w += (size_t)GN * GK * 8;
    unsigned short* Wth = (unsigned short*)w; w += (size_t)256 * 128 * 2;
    unsigned short* Wtl = (unsigned short*)w; w += (size_t)256 * 128 * 2;
    float* uvec = (float*)w; w += (size_t)4 * 128 * 4;
    float* sq   = (float*)w; w += (size_t)GN * 4;
    float* a_s  = (float*)w; w += (size_t)GN * GH * 4;
    float* a_d  = (float*)w; w += (size_t)GN * GH * 4;
    int*   fidx = (int*)w;   w += (size_t)GN * GK * 4;
    int*   cnt  = (int*)w;   w += (size_t)GN * 4;      // cnt|curs contiguous
    int*   curs = (int*)w;   w += (size_t)GN * 4;
    int*   offs = (int*)w;   w += (size_t)(GN + 1) * 4;
    int*   elst = (int*)w;   w += (size_t)GN * GK * 4;
    size_t need = (size_t)((char*)w - (char*)d_ws);
    if (ws_size < need) return;   // diagnostic guard

    k_zero<<<(2 * GN + 255) / 256, 256, 0, stream>>>(cnt, 2 * GN);
    k_uvec<<<4, 256, 0, stream>>>(W, att_src, att_dst, uvec);
    k_trans<<<128, 256, 0, stream>>>(W, Wth, Wtl);
    k_conv<<<GN / 4, 256, 0, stream>>>(x, uvec, sq, xa, xb, a_s, a_d);
    k_gemm_topk<<<dim3(64, 8), 256, 0, stream>>>(xa, xb, cand);
    k_refine<<<GN / 4, 256, 0, stream>>>(cand, x, sq, fidx, cnt);
    k_scan<<<1, 256, 0, stream>>>(cnt, offs);
    k_fill<<<GN * GK / 256, 256, 0, stream>>>(fidx, offs, curs, elst, a_s, a_d, ew);
    k_out<<<GN / 16, 512, 0, stream>>>(offs, elst, ew, x, Wth, Wtl, bias, gamma, beta, out);
}

// Round 12
// 199.379 us; speedup vs baseline: 4.6260x; 1.0927x over previous
//
#include <hip/hip_runtime.h>
#include <hip/hip_bf16.h>
#include <math.h>

#define GN 8192
#define GD 128
#define GH 2
#define GK 3
#define NEG_SLOPE 0.2f
#define LN_EPS 1e-5f

using short8  = __attribute__((ext_vector_type(8)))  short;
using float16 = __attribute__((ext_vector_type(16))) float;
using f32x4   = __attribute__((ext_vector_type(4)))  float;

__device__ __forceinline__ float wred(float v) {
    #pragma unroll
    for (int o = 32; o > 0; o >>= 1) v += __shfl_xor(v, o, 64);
    return v;
}

// monotone float->uint encoding (ascending float -> ascending uint)
__device__ __forceinline__ unsigned fenc(float f) {
    unsigned b = __float_as_uint(f);
    return (b & 0x80000000u) ? ~b : (b | 0x80000000u);
}

__device__ __forceinline__ float rawbf2f(unsigned short s) {
    return __uint_as_float(((unsigned)s) << 16);
}
__device__ __forceinline__ unsigned short f2rawbf(float f) {
    __hip_bfloat16 b = __float2bfloat16(f);
    unsigned short r; __builtin_memcpy(&r, &b, 2);
    return r;
}
__device__ __forceinline__ unsigned umin2(unsigned a, unsigned b) { return a < b ? a : b; }
__device__ __forceinline__ unsigned umax2(unsigned a, unsigned b) { return a > b ? a : b; }

__global__ void k_zero(int* p, int n) {
    int t = blockIdx.x * 256 + threadIdx.x;
    if (t < n) p[t] = 0;
}

// u vectors: uvec[b][d] = sum_c W[d][h*128+c] * v[h][c], b = {s0,s1,d0,d1}
__global__ void k_uvec(const float* __restrict__ W, const float* __restrict__ att_src,
                       const float* __restrict__ att_dst, float* __restrict__ uvec) {
    __shared__ float vs[128];
    int b = blockIdx.x, t = threadIdx.x;
    int h = b & 1;
    const float* v = (b < 2 ? att_src : att_dst) + h * 128;
    if (t < 128) vs[t] = v[t];
    __syncthreads();
    int d = t >> 1, half = t & 1;
    const float* wr = W + (size_t)d * 256 + h * 128 + half * 64;
    float s = 0.f;
    for (int c = 0; c < 64; c++) s += wr[c] * vs[half * 64 + c];
    s += __shfl_xor(s, 1, 64);
    if (half == 0) uvec[b * 128 + d] = s;
}

// W transpose into MFMA-B layout: Wt[c][k], k = h*128+d, bf16 hi/lo split
__global__ void k_trans(const float* __restrict__ W,
                        unsigned short* __restrict__ Wth, unsigned short* __restrict__ Wtl) {
    int e = blockIdx.x * 256 + threadIdx.x;   // 32768
    int d = e >> 8, j = e & 255;
    int h = j >> 7, c = j & 127;
    int k = h * 128 + d;
    float w = W[e];
    unsigned short hi = f2rawbf(w);
    Wth[c * 256 + k] = hi;
    Wtl[c * 256 + k] = f2rawbf(w - rawbf2f(hi));
}

// one wave per row: sq, xa=[-2x | hi(sq+512) lo | 0..], xb=[x | 1 1 | 0..],
// plus attention dots a_s/a_d via u-vectors.
__global__ void k_conv(const float* __restrict__ x, const float* __restrict__ uvec,
                       float* __restrict__ sq,
                       unsigned short* __restrict__ xa, unsigned short* __restrict__ xb,
                       float* __restrict__ a_s, float* __restrict__ a_d) {
    int row = blockIdx.x * 4 + (threadIdx.x >> 6);
    int lane = threadIdx.x & 63;
    const float* xr = x + (size_t)row * GD;
    float a0 = xr[lane], a1 = xr[lane + 64];
    float s = wred(a0 * a0 + a1 * a1);
    unsigned short* ar = xa + (size_t)row * 144;
    unsigned short* br = xb + (size_t)row * 144;
    ar[lane] = f2rawbf(-2.f * a0); ar[lane + 64] = f2rawbf(-2.f * a1);
    br[lane] = f2rawbf(a0);        br[lane + 64] = f2rawbf(a1);
    float s0 = wred(a0 * uvec[lane]       + a1 * uvec[64 + lane]);
    float s1 = wred(a0 * uvec[128 + lane] + a1 * uvec[192 + lane]);
    float d0 = wred(a0 * uvec[256 + lane] + a1 * uvec[320 + lane]);
    float d1 = wred(a0 * uvec[384 + lane] + a1 * uvec[448 + lane]);
    if (lane < 16) {
        unsigned short av = 0, bv = 0;
        if (lane == 0)      { av = f2rawbf(s + 512.f); bv = 0x3F80; }
        else if (lane == 1) { float hi = rawbf2f(f2rawbf(s + 512.f));
                              av = f2rawbf(s + 512.f - hi); bv = 0x3F80; }
        ar[128 + lane] = av; br[128 + lane] = bv;
        if (lane == 0) {
            sq[row] = s;
            a_s[row * 2] = s0; a_s[row * 2 + 1] = s1;
            a_d[row * 2] = d0; a_d[row * 2 + 1] = d1;
        }
    }
}

// sorted top-6 of unsigned keys, branchless bubble insert
struct Top6 {
    unsigned a0, a1, a2, a3, a4, a5;
    __device__ __forceinline__ void init() { a0=a1=a2=a3=a4=a5=0xFFFFFFFFu; }
    __device__ __forceinline__ void insert(unsigned k) {
        unsigned m0 = umax2(a0, k);  a0 = umin2(a0, k);
        unsigned m1 = umax2(a1, m0); a1 = umin2(a1, m0);
        unsigned m2 = umax2(a2, m1); a2 = umin2(a2, m1);
        unsigned m3 = umax2(a3, m2); a3 = umin2(a3, m2);
        unsigned m4 = umax2(a4, m3); a4 = umin2(a4, m3);
        a5 = umin2(a5, m4);
    }
};

// MFMA candidate kNN. score'_ij = 512 + sq_i - 2 x_i.x_j (> 0 -> raw bits monotone).
__launch_bounds__(256, 2)
__global__ void k_gemm_topk(const unsigned short* __restrict__ xa,
                            const unsigned short* __restrict__ xb,
                            unsigned* __restrict__ cand) {
    __shared__ unsigned short At[18 * 128 * 8];
    int t = threadIdx.x;
    int w = t >> 6, lane = t & 63, h = lane >> 5, n = lane & 31;
    int col = blockIdx.x * 128 + w * 32 + n;
    int sb = blockIdx.y;

    short8 bfrag[9];
    #pragma unroll
    for (int kc = 0; kc < 9; kc++)
        bfrag[kc] = *(const short8*)(xb + (size_t)col * 144 + (2 * kc + h) * 8);

    Top6 T; T.init();

    for (int it = 0; it < 8; it++) {
        int rowbase = sb * 1024 + it * 128;
        __syncthreads();
        #pragma unroll
        for (int q = t; q < 18 * 128; q += 256) {
            int kb = q >> 7, r = q & 127;
            *(uint4*)&At[(kb * 128 + r) * 8] =
                *(const uint4*)(xa + (size_t)(rowbase + r) * 144 + kb * 8);
        }
        __syncthreads();

        float16 acc[4];
        #pragma unroll
        for (int rs = 0; rs < 4; rs++) acc[rs] = (float16)(0.f);

        #pragma unroll
        for (int kc = 0; kc < 9; kc++) {
            short8 a[4];
            #pragma unroll
            for (int rs = 0; rs < 4; rs++)
                a[rs] = *(const short8*)&At[((2 * kc + h) * 128 + rs * 32 + n) * 8];
            #pragma unroll
            for (int rs = 0; rs < 4; rs++)
                acc[rs] = __builtin_amdgcn_mfma_f32_32x32x16_bf16(a[rs], bfrag[kc], acc[rs], 0, 0, 0);
        }

        #pragma unroll
        for (int rs = 0; rs < 4; rs++) {
            float16 A = acc[rs];
            int rb = rowbase + 4 * h + rs * 32;
            unsigned kk[16];
            #pragma unroll
            for (int r = 0; r < 16; r++)
                kk[r] = (__float_as_uint(A[r]) & 0xFFFFE000u) |
                        (unsigned)(rb + (r & 3) + 8 * (r >> 2));
            unsigned ma = umin2(umin2(umin2(kk[0],kk[1]),umin2(kk[2],kk[3])),
                                umin2(umin2(kk[4],kk[5]),umin2(kk[6],kk[7])));
            unsigned mb = umin2(umin2(umin2(kk[8],kk[9]),umin2(kk[10],kk[11])),
                                umin2(umin2(kk[12],kk[13]),umin2(kk[14],kk[15])));
            if (umin2(ma, mb) <= T.a5) {
                #pragma unroll
                for (int r = 0; r < 16; r++) T.insert(kk[r]);
            }
        }
    }

    unsigned p0 = (unsigned)__shfl_xor((int)T.a0, 32), p1 = (unsigned)__shfl_xor((int)T.a1, 32),
             p2 = (unsigned)__shfl_xor((int)T.a2, 32), p3 = (unsigned)__shfl_xor((int)T.a3, 32),
             p4 = (unsigned)__shfl_xor((int)T.a4, 32), p5 = (unsigned)__shfl_xor((int)T.a5, 32);
    T.insert(p0); T.insert(p1); T.insert(p2); T.insert(p3); T.insert(p4); T.insert(p5);

    if (h == 0) {
        unsigned* c0 = cand + (size_t)col * 48 + sb * 6;
        c0[0]=T.a0; c0[1]=T.a1; c0[2]=T.a2; c0[3]=T.a3; c0[4]=T.a4; c0[5]=T.a5;
    }
}

__device__ __forceinline__ int clampN(int v) {
    return v < 0 ? 0 : (v >= GN ? GN - 1 : v);
}

// exact fp32 refine + degree count. One wave per node; lane c owns candidate c.
__global__ void k_refine(const unsigned* __restrict__ cand,
                         const float* __restrict__ x, const float* __restrict__ sq,
                         int* __restrict__ fidx, int* __restrict__ cnt) {
    __shared__ float xjs[4][132];
    int t = threadIdx.x, wv = t >> 6, lane = t & 63;
    int j = blockIdx.x * 4 + wv;
    xjs[wv][lane] = x[(size_t)j * GD + lane];
    xjs[wv][64 + lane] = x[(size_t)j * GD + 64 + lane];
    float sqj = sq[j];
    unsigned long long key = ~0ull;
    if (lane < 48) {
        int idx = (int)(cand[(size_t)j * 48 + lane] & 8191u);
        const float* xi = x + (size_t)idx * GD;
        float p = 0.f;
        #pragma unroll
        for (int d4 = 0; d4 < 32; d4++) {
            float4 a = *(const float4*)(xi + d4 * 4);
            float4 b = *(const float4*)&xjs[wv][d4 * 4];
            p += a.x * b.x + a.y * b.y + a.z * b.z + a.w * b.w;
        }
        float d2 = sqj + sq[idx] - 2.f * p;
        key = ((unsigned long long)fenc(d2) << 32) | (unsigned)idx;
    }
    int out3[3];
    #pragma unroll
    for (int r = 0; r < 3; r++) {
        unsigned long long k = key;
        #pragma unroll
        for (int o = 32; o > 0; o >>= 1) {
            unsigned long long other = __shfl_xor(k, o, 64);
            k = k < other ? k : other;
        }
        out3[r] = (int)(unsigned)(k & 0xffffffffu);
        key = (key == k) ? ~0ull : key;
    }
    if (lane == 0) {
        int i0 = clampN(out3[0]), i1 = clampN(out3[1]), i2 = clampN(out3[2]);
        fidx[j * 3 + 0] = i0; fidx[j * 3 + 1] = i1; fidx[j * 3 + 2] = i2;
        atomicAdd(&cnt[i0], 1); atomicAdd(&cnt[i1], 1); atomicAdd(&cnt[i2], 1);
    }
}

__global__ void k_scan(const int* __restrict__ cnt, int* __restrict__ offs) {
    __shared__ int part[256];
    int t = threadIdx.x;
    int base = t * 32;
    int loc[32];
    int s = 0;
    #pragma unroll
    for (int k = 0; k < 32; k++) { loc[k] = s; s += cnt[base + k]; }
    part[t] = s;
    __syncthreads();
    if (t == 0) {
        int run = 0;
        for (int k = 0; k < 256; k++) { int v = part[k]; part[k] = run; run += v; }
        offs[GN] = run;
    }
    __syncthreads();
    int b = part[t];
    #pragma unroll
    for (int k = 0; k < 32; k++) offs[base + k] = b + loc[k];
}

// edge-parallel fill: CSR scatter + per-edge UNNORMALIZED softmax weights
// ew[slot] = (exp(leaky(e0)), exp(leaky(e1))) — no max shift (e ~ N(0,2), safe in fp32;
// ratios w/sum(w) identical to the reference's max-shifted form).
__global__ void k_fill(const int* __restrict__ fidx, const int* __restrict__ offs,
                       int* __restrict__ cursor, int* __restrict__ elist,
                       const float* __restrict__ a_s, const float* __restrict__ a_d,
                       float2* __restrict__ ew) {
    int eid = blockIdx.x * 256 + threadIdx.x;
    int i = clampN(fidx[eid]);
    int src = eid / 3;
    float2 as = ((const float2*)a_s)[src];
    float2 ad = ((const float2*)a_d)[i];
    float e0 = as.x + ad.x; e0 = e0 >= 0.f ? e0 : NEG_SLOPE * e0;
    float e1 = as.y + ad.y; e1 = e1 >= 0.f ? e1 : NEG_SLOPE * e1;
    float w0 = expf(e0), w1 = expf(e1);
    int pos = atomicAdd(&cursor[i], 1);
    int slot = offs[i] + pos;
    if (slot < GN * GK) { elist[slot] = src; ew[slot] = make_float2(w0, w1); }
}

// fused aggregation: 16 nodes/block, 512 threads (8 waves; 2 nodes/wave).
// phase A: EDGE-PARALLEL z: lane = eslot*8+g; 8 edges in flight x 16 dims/lane;
//          denom folds out of the same xor-reduction (hub nodes 8x faster).
// phase B: MFMA GEMM y = z@Wt (err-compensated bf16 hi/lo).
// phase C: bias + LN + ReLU + residual.
__launch_bounds__(512, 4)
__global__ void k_out(const int* __restrict__ offs, const int* __restrict__ elst,
                      const float2* __restrict__ ew,
                      const float* __restrict__ x,
                      const unsigned short* __restrict__ Wth,
                      const unsigned short* __restrict__ Wtl,
                      const float* __restrict__ bias, const float* __restrict__ gamma,
                      const float* __restrict__ beta, float* __restrict__ out) {
    __shared__ unsigned short zh[16][264];
    __shared__ unsigned short zl[16][264];
    __shared__ float os[16][132];
    int t = threadIdx.x, i0 = blockIdx.x * 16;
    int wv = t >> 6, lane = t & 63;   // wv 0..7
    int eslot = lane >> 3, g = lane & 7;   // 8 edge-slots x 8 dim-groups

    #pragma unroll
    for (int pp = 0; pp < 2; pp++) {
        int r = wv * 2 + pp, node = i0 + r;
        int s = offs[node], e = offs[node + 1];
        float acc0[16], acc1[16];
        #pragma unroll
        for (int q = 0; q < 16; q++) { acc0[q] = 0.f; acc1[q] = 0.f; }
        float w0s = 0.f, w1s = 0.f;
        for (int k0 = s; k0 < e; k0 += 8) {
            int k = k0 + eslot;
            bool valid = k < e;
            int j = valid ? elst[k] : 0;
            float2 wv2 = valid ? ew[k] : make_float2(0.f, 0.f);
            const float* xr = x + (size_t)j * GD + g * 16;
            float4 x0 = *(const float4*)(xr);
            float4 x1 = *(const float4*)(xr + 4);
            float4 x2 = *(const float4*)(xr + 8);
            float4 x3 = *(const float4*)(xr + 12);
            float xv[16] = {x0.x, x0.y, x0.z, x0.w, x1.x, x1.y, x1.z, x1.w,
                            x2.x, x2.y, x2.z, x2.w, x3.x, x3.y, x3.z, x3.w};
            #pragma unroll
            for (int q = 0; q < 16; q++) {
                acc0[q] += wv2.x * xv[q];
                acc1[q] += wv2.y * xv[q];
            }
            w0s += wv2.x; w1s += wv2.y;
        }
        // reduce over the 8 edge-slots (lane bits 3..5)
        #pragma unroll
        for (int m = 8; m <= 32; m <<= 1) {
            #pragma unroll
            for (int q = 0; q < 16; q++) {
                acc0[q] += __shfl_xor(acc0[q], m, 64);
                acc1[q] += __shfl_xor(acc1[q], m, 64);
            }
            w0s += __shfl_xor(w0s, m, 64);
            w1s += __shfl_xor(w1s, m, 64);
        }
        if (lane < 8) {   // lane == g, eslot == 0; holds full sums for dims g*16..+15
            float dn0 = 0.5f / w0s, dn1 = 0.5f / w1s;
            #pragma unroll
            for (int q = 0; q < 16; q += 2) {
                float a0 = acc0[q] * dn0, a1 = acc0[q + 1] * dn0;
                unsigned short h0 = f2rawbf(a0), h1 = f2rawbf(a1);
                *(unsigned*)&zh[r][lane * 16 + q] = (unsigned)h0 | ((unsigned)h1 << 16);
                *(unsigned*)&zl[r][lane * 16 + q] =
                    (unsigned)f2rawbf(a0 - rawbf2f(h0)) |
                    ((unsigned)f2rawbf(a1 - rawbf2f(h1)) << 16);
                float b0 = acc1[q] * dn1, b1 = acc1[q + 1] * dn1;
                unsigned short p0 = f2rawbf(b0), p1 = f2rawbf(b1);
                *(unsigned*)&zh[r][128 + lane * 16 + q] = (unsigned)p0 | ((unsigned)p1 << 16);
                *(unsigned*)&zl[r][128 + lane * 16 + q] =
                    (unsigned)f2rawbf(b0 - rawbf2f(p0)) |
                    ((unsigned)f2rawbf(b1 - rawbf2f(p1)) << 16);
            }
        }
    }
    __syncthreads();

    // phase B: y[16][128] = z[16][256] @ Wt[256][128]; wave wv owns 16-col group
    {
        int qd = lane >> 4, an = lane & 15;
        int c = wv * 16 + an;
        f32x4 acc = {0.f, 0.f, 0.f, 0.f};
        #pragma unroll
        for (int s = 0; s < 8; s++) {
            int ko = s * 32 + qd * 8;
            short8 ah = *(const short8*)&zh[an][ko];
            short8 al = *(const short8*)&zl[an][ko];
            short8 bh = *(const short8*)(Wth + (size_t)c * 256 + ko);
            short8 bl = *(const short8*)(Wtl + (size_t)c * 256 + ko);
            acc = __builtin_amdgcn_mfma_f32_16x16x32_bf16(ah, bh, acc, 0, 0, 0);
            acc = __builtin_amdgcn_mfma_f32_16x16x32_bf16(al, bh, acc, 0, 0, 0);
            acc = __builtin_amdgcn_mfma_f32_16x16x32_bf16(ah, bl, acc, 0, 0, 0);
        }
        #pragma unroll
        for (int r = 0; r < 4; r++) os[qd * 4 + r][c] = acc[r];
    }
    __syncthreads();

    // phase C: bias + LN + ReLU + residual (2 nodes per wave)
    #pragma unroll
    for (int pp = 0; pp < 2; pp++) {
        int r = wv * 2 + pp, node = i0 + r;
        float y0 = os[r][lane] + bias[lane];
        float y1 = os[r][lane + 64] + bias[lane + 64];
        float mu = wred(y0 + y1) * (1.f / 128.f);
        float c0 = y0 - mu, c1 = y1 - mu;
        float var = wred(c0 * c0 + c1 * c1) * (1.f / 128.f);
        float rs2 = 1.f / sqrtf(var + LN_EPS);
        float n0 = c0 * rs2 * gamma[lane] + beta[lane];
        float n1 = c1 * rs2 * gamma[lane + 64] + beta[lane + 64];
        n0 = n0 > 0.f ? n0 : 0.f;
        n1 = n1 > 0.f ? n1 : 0.f;
        out[(size_t)node * GD + lane]      = x[(size_t)node * GD + lane] + n0;
        out[(size_t)node * GD + lane + 64] = x[(size_t)node * GD + lane + 64] + n1;
    }
}

extern "C" void kernel_launch(void* const* d_in, const int* in_sizes, int n_in,
                              void* d_out, int out_size, void* d_ws, size_t ws_size,
                              hipStream_t stream) {
    const float* x       = (const float*)d_in[0];
    const float* W       = (const float*)d_in[2];
    const float* att_src = (const float*)d_in[3];
    const float* att_dst = (const float*)d_in[4];
    const float* bias    = (const float*)d_in[5];
    const float* gamma   = (const float*)d_in[6];
    const float* beta    = (const float*)d_in[7];
    float* out = (float*)d_out;

    char* w = (char*)d_ws;
    unsigned short* xa = (unsigned short*)w; w += (size_t)GN * 144 * 2;
    unsigned short* xb = (unsigned short*)w; w += (size_t)GN * 144 * 2;
    unsigned* cand = (unsigned*)w;           w += (size_t)GN * 48 * 4;
    float2* ew  = (float2*)w; w += (size_t)GN * GK * 8;
    unsigned short* Wth = (unsigned short*)w; w += (size_t)256 * 128 * 2;
    unsigned short* Wtl = (unsigned short*)w; w += (size_t)256 * 128 * 2;
    float* uvec = (float*)w; w += (size_t)4 * 128 * 4;
    float* sq   = (float*)w; w += (size_t)GN * 4;
    float* a_s  = (float*)w; w += (size_t)GN * GH * 4;
    float* a_d  = (float*)w; w += (size_t)GN * GH * 4;
    int*   fidx = (int*)w;   w += (size_t)GN * GK * 4;
    int*   cnt  = (int*)w;   w += (size_t)GN * 4;      // cnt|curs contiguous
    int*   curs = (int*)w;   w += (size_t)GN * 4;
    int*   offs = (int*)w;   w += (size_t)(GN + 1) * 4;
    int*   elst = (int*)w;   w += (size_t)GN * GK * 4;
    size_t need = (size_t)((char*)w - (char*)d_ws);
    if (ws_size < need) return;   // diagnostic guard

    k_zero<<<(2 * GN + 255) / 256, 256, 0, stream>>>(cnt, 2 * GN);
    k_uvec<<<4, 256, 0, stream>>>(W, att_src, att_dst, uvec);
    k_trans<<<128, 256, 0, stream>>>(W, Wth, Wtl);
    k_conv<<<GN / 4, 256, 0, stream>>>(x, uvec, sq, xa, xb, a_s, a_d);
    k_gemm_topk<<<dim3(64, 8), 256, 0, stream>>>(xa, xb, cand);
    k_refine<<<GN / 4, 256, 0, stream>>>(cand, x, sq, fidx, cnt);
    k_scan<<<1, 256, 0, stream>>>(cnt, offs);
    k_fill<<<GN * GK / 256, 256, 0, stream>>>(fidx, offs, curs, elst, a_s, a_d, ew);
    k_out<<<GN / 16, 512, 0, stream>>>(offs, elst, ew, x, Wth, Wtl, bias, gamma, beta, out);
}

// Round 13
// 192.702 us; speedup vs baseline: 4.7862x; 1.0346x over previous
//
#include <hip/hip_runtime.h>
#include <hip/hip_bf16.h>
#include <math.h>

#define GN 8192
#define GD 128
#define GH 2
#define GK 3
#define NEG_SLOPE 0.2f
#define LN_EPS 1e-5f

using short8  = __attribute__((ext_vector_type(8)))  short;
using float16 = __attribute__((ext_vector_type(16))) float;
using f32x4   = __attribute__((ext_vector_type(4)))  float;

__device__ __forceinline__ float wred(float v) {
    #pragma unroll
    for (int o = 32; o > 0; o >>= 1) v += __shfl_xor(v, o, 64);
    return v;
}

// monotone float->uint encoding (ascending float -> ascending uint)
__device__ __forceinline__ unsigned fenc(float f) {
    unsigned b = __float_as_uint(f);
    return (b & 0x80000000u) ? ~b : (b | 0x80000000u);
}

__device__ __forceinline__ float rawbf2f(unsigned short s) {
    return __uint_as_float(((unsigned)s) << 16);
}
__device__ __forceinline__ unsigned short f2rawbf(float f) {
    __hip_bfloat16 b = __float2bfloat16(f);
    unsigned short r; __builtin_memcpy(&r, &b, 2);
    return r;
}
__device__ __forceinline__ unsigned umin2(unsigned a, unsigned b) { return a < b ? a : b; }
__device__ __forceinline__ unsigned umax2(unsigned a, unsigned b) { return a > b ? a : b; }

// merged pre-pass: blocks 0..127 transpose W into MFMA-B bf16 hi/lo; blocks 128..131
// compute u vectors uvec[b][d] = sum_c W[d][h*128+c] * v[h][c], b = {s0,s1,d0,d1}
__global__ void k_pre(const float* __restrict__ W, const float* __restrict__ att_src,
                      const float* __restrict__ att_dst,
                      unsigned short* __restrict__ Wth, unsigned short* __restrict__ Wtl,
                      float* __restrict__ uvec) {
    __shared__ float vs[128];
    int b = blockIdx.x, t = threadIdx.x;
    if (b < 128) {
        int e = b * 256 + t;   // 32768
        int d = e >> 8, j = e & 255;
        int h = j >> 7, c = j & 127;
        int k = h * 128 + d;
        float w = W[e];
        unsigned short hi = f2rawbf(w);
        Wth[c * 256 + k] = hi;
        Wtl[c * 256 + k] = f2rawbf(w - rawbf2f(hi));
    } else {
        int bb = b - 128;
        int h = bb & 1;
        const float* v = (bb < 2 ? att_src : att_dst) + h * 128;
        if (t < 128) vs[t] = v[t];
        __syncthreads();
        int d = t >> 1, half = t & 1;
        const float* wr = W + (size_t)d * 256 + h * 128 + half * 64;
        float s = 0.f;
        for (int c = 0; c < 64; c++) s += wr[c] * vs[half * 64 + c];
        s += __shfl_xor(s, 1, 64);
        if (half == 0) uvec[bb * 128 + d] = s;
    }
}

// one wave per row: sq, xa=[-2x | hi(sq+512) lo | 0..], xb=[x | 1 1 | 0..],
// attention dots a_s/a_d via u-vectors, and zero-init of cnt/curs (k_zero folded in).
__global__ void k_conv(const float* __restrict__ x, const float* __restrict__ uvec,
                       float* __restrict__ sq,
                       unsigned short* __restrict__ xa, unsigned short* __restrict__ xb,
                       float* __restrict__ a_s, float* __restrict__ a_d,
                       int* __restrict__ cnt, int* __restrict__ curs) {
    int row = blockIdx.x * 4 + (threadIdx.x >> 6);
    int lane = threadIdx.x & 63;
    const float* xr = x + (size_t)row * GD;
    float a0 = xr[lane], a1 = xr[lane + 64];
    float s = wred(a0 * a0 + a1 * a1);
    unsigned short* ar = xa + (size_t)row * 144;
    unsigned short* br = xb + (size_t)row * 144;
    ar[lane] = f2rawbf(-2.f * a0); ar[lane + 64] = f2rawbf(-2.f * a1);
    br[lane] = f2rawbf(a0);        br[lane + 64] = f2rawbf(a1);
    float s0 = wred(a0 * uvec[lane]       + a1 * uvec[64 + lane]);
    float s1 = wred(a0 * uvec[128 + lane] + a1 * uvec[192 + lane]);
    float d0 = wred(a0 * uvec[256 + lane] + a1 * uvec[320 + lane]);
    float d1 = wred(a0 * uvec[384 + lane] + a1 * uvec[448 + lane]);
    if (lane < 16) {
        unsigned short av = 0, bv = 0;
        if (lane == 0)      { av = f2rawbf(s + 512.f); bv = 0x3F80; }
        else if (lane == 1) { float hi = rawbf2f(f2rawbf(s + 512.f));
                              av = f2rawbf(s + 512.f - hi); bv = 0x3F80; }
        ar[128 + lane] = av; br[128 + lane] = bv;
        if (lane == 0) {
            sq[row] = s;
            a_s[row * 2] = s0; a_s[row * 2 + 1] = s1;
            a_d[row * 2] = d0; a_d[row * 2 + 1] = d1;
            cnt[row] = 0; curs[row] = 0;
        }
    }
}

// MFMA candidate kNN. score'_ij = 512 + sq_i - 2 x_i.x_j (> 0 -> raw bits monotone).
// grid (64,16): 128 cols x 512-row superblock per block; top-4/superblock/col.
// Async global->LDS staging; raw-bit frag-min pre-filter before key packing.
__launch_bounds__(256, 4)
__global__ void k_gemm_topk(const unsigned short* __restrict__ xa,
                            const unsigned short* __restrict__ xb,
                            unsigned* __restrict__ cand) {
    __shared__ unsigned short At[18 * 128 * 8];   // 36 KB, k-major 16B chunks
    int t = threadIdx.x;
    int w = t >> 6, lane = t & 63, h = lane >> 5, n = lane & 31;
    int col = blockIdx.x * 128 + w * 32 + n;
    int sb = blockIdx.y;   // 0..15

    short8 bfrag[9];
    #pragma unroll
    for (int kc = 0; kc < 9; kc++)
        bfrag[kc] = *(const short8*)(xb + (size_t)col * 144 + (2 * kc + h) * 8);

    unsigned T0 = 0xFFFFFFFFu, T1 = 0xFFFFFFFFu, T2 = 0xFFFFFFFFu, T3 = 0xFFFFFFFFu;

    for (int it = 0; it < 4; it++) {
        int rowbase = sb * 512 + it * 128;
        __syncthreads();
        #pragma unroll
        for (int s = 0; s < 9; s++) {
            int q = t + 256 * s;               // 0..2303
            int kb = q >> 7, r = q & 127;
            __builtin_amdgcn_global_load_lds(
                (const __attribute__((address_space(1))) unsigned*)
                    (xa + (size_t)(rowbase + r) * 144 + kb * 8),
                (__attribute__((address_space(3))) unsigned*)&At[q * 8],
                16, 0, 0);
        }
        __syncthreads();

        float16 acc[4];
        #pragma unroll
        for (int rs = 0; rs < 4; rs++) acc[rs] = (float16)(0.f);

        #pragma unroll
        for (int kc = 0; kc < 9; kc++) {
            short8 a[4];
            #pragma unroll
            for (int rs = 0; rs < 4; rs++)
                a[rs] = *(const short8*)&At[((2 * kc + h) * 128 + rs * 32 + n) * 8];
            #pragma unroll
            for (int rs = 0; rs < 4; rs++)
                acc[rs] = __builtin_amdgcn_mfma_f32_32x32x16_bf16(a[rs], bfrag[kc], acc[rs], 0, 0, 0);
        }

        #pragma unroll
        for (int rs = 0; rs < 4; rs++) {
            float16 A = acc[rs];
            // raw-bit min filter (scores > 0 -> bits monotone); pack keys only on pass
            unsigned b[16];
            #pragma unroll
            for (int r = 0; r < 16; r++) b[r] = __float_as_uint(A[r]);
            unsigned ma = umin2(umin2(umin2(b[0],b[1]),umin2(b[2],b[3])),
                                umin2(umin2(b[4],b[5]),umin2(b[6],b[7])));
            unsigned mb = umin2(umin2(umin2(b[8],b[9]),umin2(b[10],b[11])),
                                umin2(umin2(b[12],b[13]),umin2(b[14],b[15])));
            if ((umin2(ma, mb) & 0xFFFFE000u) <= T3) {
                int rb = rowbase + 4 * h + rs * 32;
                #pragma unroll
                for (int r = 0; r < 16; r++) {
                    unsigned k = (b[r] & 0xFFFFE000u) |
                                 (unsigned)(rb + (r & 3) + 8 * (r >> 2));
                    unsigned m0 = umax2(T0, k);  T0 = umin2(T0, k);
                    unsigned m1 = umax2(T1, m0); T1 = umin2(T1, m0);
                    unsigned m2 = umax2(T2, m1); T2 = umin2(T2, m1);
                    T3 = umin2(T3, m2);
                }
            }
        }
    }

    // merge the two h-halves of each column
    unsigned p0 = (unsigned)__shfl_xor((int)T0, 32), p1 = (unsigned)__shfl_xor((int)T1, 32),
             p2 = (unsigned)__shfl_xor((int)T2, 32), p3 = (unsigned)__shfl_xor((int)T3, 32);
    #pragma unroll
    for (int q = 0; q < 4; q++) {
        unsigned k = (q == 0) ? p0 : (q == 1) ? p1 : (q == 2) ? p2 : p3;
        unsigned m0 = umax2(T0, k);  T0 = umin2(T0, k);
        unsigned m1 = umax2(T1, m0); T1 = umin2(T1, m0);
        unsigned m2 = umax2(T2, m1); T2 = umin2(T2, m1);
        T3 = umin2(T3, m2);
    }

    if (h == 0) {
        uint4 o = make_uint4(T0, T1, T2, T3);
        *(uint4*)(cand + (size_t)col * 64 + sb * 4) = o;
    }
}

__device__ __forceinline__ int clampN(int v) {
    return v < 0 ? 0 : (v >= GN ? GN - 1 : v);
}

// exact fp32 refine + degree count. One wave per node; lane owns candidate lane (64).
__global__ void k_refine(const unsigned* __restrict__ cand,
                         const float* __restrict__ x, const float* __restrict__ sq,
                         int* __restrict__ fidx, int* __restrict__ cnt) {
    __shared__ float xjs[4][132];
    int t = threadIdx.x, wv = t >> 6, lane = t & 63;
    int j = blockIdx.x * 4 + wv;
    xjs[wv][lane] = x[(size_t)j * GD + lane];
    xjs[wv][64 + lane] = x[(size_t)j * GD + 64 + lane];
    float sqj = sq[j];
    int idx = (int)(cand[(size_t)j * 64 + lane] & 8191u);
    const float* xi = x + (size_t)idx * GD;
    float p = 0.f;
    #pragma unroll
    for (int d4 = 0; d4 < 32; d4++) {
        float4 a = *(const float4*)(xi + d4 * 4);
        float4 b = *(const float4*)&xjs[wv][d4 * 4];
        p += a.x * b.x + a.y * b.y + a.z * b.z + a.w * b.w;
    }
    float d2 = sqj + sq[idx] - 2.f * p;
    unsigned long long key = ((unsigned long long)fenc(d2) << 32) | (unsigned)idx;
    int out3[3];
    #pragma unroll
    for (int r = 0; r < 3; r++) {
        unsigned long long k = key;
        #pragma unroll
        for (int o = 32; o > 0; o >>= 1) {
            unsigned long long other = __shfl_xor(k, o, 64);
            k = k < other ? k : other;
        }
        out3[r] = (int)(unsigned)(k & 0xffffffffu);
        key = (key == k) ? ~0ull : key;   // keys unique per node (distinct idx)
    }
    if (lane == 0) {
        int i0 = clampN(out3[0]), i1 = clampN(out3[1]), i2 = clampN(out3[2]);
        fidx[j * 3 + 0] = i0; fidx[j * 3 + 1] = i1; fidx[j * 3 + 2] = i2;
        atomicAdd(&cnt[i0], 1); atomicAdd(&cnt[i1], 1); atomicAdd(&cnt[i2], 1);
    }
}

__global__ void k_scan(const int* __restrict__ cnt, int* __restrict__ offs) {
    __shared__ int part[256];
    int t = threadIdx.x;
    int base = t * 32;
    int loc[32];
    int s = 0;
    #pragma unroll
    for (int k = 0; k < 32; k++) { loc[k] = s; s += cnt[base + k]; }
    part[t] = s;
    __syncthreads();
    if (t == 0) {
        int run = 0;
        for (int k = 0; k < 256; k++) { int v = part[k]; part[k] = run; run += v; }
        offs[GN] = run;
    }
    __syncthreads();
    int b = part[t];
    #pragma unroll
    for (int k = 0; k < 32; k++) offs[base + k] = b + loc[k];
}

// edge-parallel fill: CSR scatter + per-edge UNNORMALIZED softmax weights
// ew[slot] = (exp(leaky(e0)), exp(leaky(e1))) — ratios identical to max-shifted form.
__global__ void k_fill(const int* __restrict__ fidx, const int* __restrict__ offs,
                       int* __restrict__ cursor, int* __restrict__ elist,
                       const float* __restrict__ a_s, const float* __restrict__ a_d,
                       float2* __restrict__ ew) {
    int eid = blockIdx.x * 256 + threadIdx.x;
    int i = clampN(fidx[eid]);
    int src = eid / 3;
    float2 as = ((const float2*)a_s)[src];
    float2 ad = ((const float2*)a_d)[i];
    float e0 = as.x + ad.x; e0 = e0 >= 0.f ? e0 : NEG_SLOPE * e0;
    float e1 = as.y + ad.y; e1 = e1 >= 0.f ? e1 : NEG_SLOPE * e1;
    float w0 = expf(e0), w1 = expf(e1);
    int pos = atomicAdd(&cursor[i], 1);
    int slot = offs[i] + pos;
    if (slot < GN * GK) { elist[slot] = src; ew[slot] = make_float2(w0, w1); }
}

// fused aggregation: 16 nodes/block, 512 threads (8 waves; 2 nodes/wave).
// phase A: edge-parallel z (8 edge-slots x 8 dim-groups per wave).
// phase B: MFMA GEMM y = z@Wt (err-compensated bf16 hi/lo).
// phase C: bias + LN + ReLU + residual.
__launch_bounds__(512, 4)
__global__ void k_out(const int* __restrict__ offs, const int* __restrict__ elst,
                      const float2* __restrict__ ew,
                      const float* __restrict__ x,
                      const unsigned short* __restrict__ Wth,
                      const unsigned short* __restrict__ Wtl,
                      const float* __restrict__ bias, const float* __restrict__ gamma,
                      const float* __restrict__ beta, float* __restrict__ out) {
    __shared__ unsigned short zh[16][264];
    __shared__ unsigned short zl[16][264];
    __shared__ float os[16][132];
    int t = threadIdx.x, i0 = blockIdx.x * 16;
    int wv = t >> 6, lane = t & 63;
    int eslot = lane >> 3, g = lane & 7;

    #pragma unroll
    for (int pp = 0; pp < 2; pp++) {
        int r = wv * 2 + pp, node = i0 + r;
        int s = offs[node], e = offs[node + 1];
        float acc0[16], acc1[16];
        #pragma unroll
        for (int q = 0; q < 16; q++) { acc0[q] = 0.f; acc1[q] = 0.f; }
        float w0s = 0.f, w1s = 0.f;
        for (int k0 = s; k0 < e; k0 += 8) {
            int k = k0 + eslot;
            bool valid = k < e;
            int j = valid ? elst[k] : 0;
            float2 wv2 = valid ? ew[k] : make_float2(0.f, 0.f);
            const float* xr = x + (size_t)j * GD + g * 16;
            float4 x0 = *(const float4*)(xr);
            float4 x1 = *(const float4*)(xr + 4);
            float4 x2 = *(const float4*)(xr + 8);
            float4 x3 = *(const float4*)(xr + 12);
            float xv[16] = {x0.x, x0.y, x0.z, x0.w, x1.x, x1.y, x1.z, x1.w,
                            x2.x, x2.y, x2.z, x2.w, x3.x, x3.y, x3.z, x3.w};
            #pragma unroll
            for (int q = 0; q < 16; q++) {
                acc0[q] += wv2.x * xv[q];
                acc1[q] += wv2.y * xv[q];
            }
            w0s += wv2.x; w1s += wv2.y;
        }
        #pragma unroll
        for (int m = 8; m <= 32; m <<= 1) {
            #pragma unroll
            for (int q = 0; q < 16; q++) {
                acc0[q] += __shfl_xor(acc0[q], m, 64);
                acc1[q] += __shfl_xor(acc1[q], m, 64);
            }
            w0s += __shfl_xor(w0s, m, 64);
            w1s += __shfl_xor(w1s, m, 64);
        }
        if (lane < 8) {
            float dn0 = 0.5f / w0s, dn1 = 0.5f / w1s;
            #pragma unroll
            for (int q = 0; q < 16; q += 2) {
                float a0 = acc0[q] * dn0, a1 = acc0[q + 1] * dn0;
                unsigned short h0 = f2rawbf(a0), h1 = f2rawbf(a1);
                *(unsigned*)&zh[r][lane * 16 + q] = (unsigned)h0 | ((unsigned)h1 << 16);
                *(unsigned*)&zl[r][lane * 16 + q] =
                    (unsigned)f2rawbf(a0 - rawbf2f(h0)) |
                    ((unsigned)f2rawbf(a1 - rawbf2f(h1)) << 16);
                float b0 = acc1[q] * dn1, b1 = acc1[q + 1] * dn1;
                unsigned short p0 = f2rawbf(b0), p1 = f2rawbf(b1);
                *(unsigned*)&zh[r][128 + lane * 16 + q] = (unsigned)p0 | ((unsigned)p1 << 16);
                *(unsigned*)&zl[r][128 + lane * 16 + q] =
                    (unsigned)f2rawbf(b0 - rawbf2f(p0)) |
                    ((unsigned)f2rawbf(b1 - rawbf2f(p1)) << 16);
            }
        }
    }
    __syncthreads();

    {
        int qd = lane >> 4, an = lane & 15;
        int c = wv * 16 + an;
        f32x4 acc = {0.f, 0.f, 0.f, 0.f};
        #pragma unroll
        for (int s = 0; s < 8; s++) {
            int ko = s * 32 + qd * 8;
            short8 ah = *(const short8*)&zh[an][ko];
            short8 al = *(const short8*)&zl[an][ko];
            short8 bh = *(const short8*)(Wth + (size_t)c * 256 + ko);
            short8 bl = *(const short8*)(Wtl + (size_t)c * 256 + ko);
            acc = __builtin_amdgcn_mfma_f32_16x16x32_bf16(ah, bh, acc, 0, 0, 0);
            acc = __builtin_amdgcn_mfma_f32_16x16x32_bf16(al, bh, acc, 0, 0, 0);
            acc = __builtin_amdgcn_mfma_f32_16x16x32_bf16(ah, bl, acc, 0, 0, 0);
        }
        #pragma unroll
        for (int r = 0; r < 4; r++) os[qd * 4 + r][c] = acc[r];
    }
    __syncthreads();

    #pragma unroll
    for (int pp = 0; pp < 2; pp++) {
        int r = wv * 2 + pp, node = i0 + r;
        float y0 = os[r][lane] + bias[lane];
        float y1 = os[r][lane + 64] + bias[lane + 64];
        float mu = wred(y0 + y1) * (1.f / 128.f);
        float c0 = y0 - mu, c1 = y1 - mu;
        float var = wred(c0 * c0 + c1 * c1) * (1.f / 128.f);
        float rs2 = 1.f / sqrtf(var + LN_EPS);
        float n0 = c0 * rs2 * gamma[lane] + beta[lane];
        float n1 = c1 * rs2 * gamma[lane + 64] + beta[lane + 64];
        n0 = n0 > 0.f ? n0 : 0.f;
        n1 = n1 > 0.f ? n1 : 0.f;
        out[(size_t)node * GD + lane]      = x[(size_t)node * GD + lane] + n0;
        out[(size_t)node * GD + lane + 64] = x[(size_t)node * GD + lane + 64] + n1;
    }
}

extern "C" void kernel_launch(void* const* d_in, const int* in_sizes, int n_in,
                              void* d_out, int out_size, void* d_ws, size_t ws_size,
                              hipStream_t stream) {
    const float* x       = (const float*)d_in[0];
    const float* W       = (const float*)d_in[2];
    const float* att_src = (const float*)d_in[3];
    const float* att_dst = (const float*)d_in[4];
    const float* bias    = (const float*)d_in[5];
    const float* gamma   = (const float*)d_in[6];
    const float* beta    = (const float*)d_in[7];
    float* out = (float*)d_out;

    char* w = (char*)d_ws;
    unsigned short* xa = (unsigned short*)w; w += (size_t)GN * 144 * 2;
    unsigned short* xb = (unsigned short*)w; w += (size_t)GN * 144 * 2;
    unsigned* cand = (unsigned*)w;           w += (size_t)GN * 64 * 4;    // 2 MB
    float2* ew  = (float2*)w; w += (size_t)GN * GK * 8;
    unsigned short* Wth = (unsigned short*)w; w += (size_t)256 * 128 * 2;
    unsigned short* Wtl = (unsigned short*)w; w += (size_t)256 * 128 * 2;
    float* uvec = (float*)w; w += (size_t)4 * 128 * 4;
    float* sq   = (float*)w; w += (size_t)GN * 4;
    float* a_s  = (float*)w; w += (size_t)GN * GH * 4;
    float* a_d  = (float*)w; w += (size_t)GN * GH * 4;
    int*   fidx = (int*)w;   w += (size_t)GN * GK * 4;
    int*   cnt  = (int*)w;   w += (size_t)GN * 4;
    int*   curs = (int*)w;   w += (size_t)GN * 4;
    int*   offs = (int*)w;   w += (size_t)(GN + 1) * 4;
    int*   elst = (int*)w;   w += (size_t)GN * GK * 4;
    size_t need = (size_t)((char*)w - (char*)d_ws);
    if (ws_size < need) return;   // diagnostic guard

    k_pre<<<132, 256, 0, stream>>>(W, att_src, att_dst, Wth, Wtl, uvec);
    k_conv<<<GN / 4, 256, 0, stream>>>(x, uvec, sq, xa, xb, a_s, a_d, cnt, curs);
    k_gemm_topk<<<dim3(64, 16), 256, 0, stream>>>(xa, xb, cand);
    k_refine<<<GN / 4, 256, 0, stream>>>(cand, x, sq, fidx, cnt);
    k_scan<<<1, 256, 0, stream>>>(cnt, offs);
    k_fill<<<GN * GK / 256, 256, 0, stream>>>(fidx, offs, curs, elst, a_s, a_d, ew);
    k_out<<<GN / 16, 512, 0, stream>>>(offs, elst, ew, x, Wth, Wtl, bias, gamma, beta, out);
}

// Round 14
// 174.835 us; speedup vs baseline: 5.2754x; 1.1022x over previous
//
#include <hip/hip_runtime.h>
#include <hip/hip_bf16.h>
#include <math.h>

#define GN 8192
#define GD 128
#define GH 2
#define GK 3
#define NEG_SLOPE 0.2f
#define LN_EPS 1e-5f

using short8  = __attribute__((ext_vector_type(8)))  short;
using float16 = __attribute__((ext_vector_type(16))) float;
using f32x4   = __attribute__((ext_vector_type(4)))  float;

__device__ __forceinline__ float wred(float v) {
    #pragma unroll
    for (int o = 32; o > 0; o >>= 1) v += __shfl_xor(v, o, 64);
    return v;
}

// monotone float->uint encoding (ascending float -> ascending uint)
__device__ __forceinline__ unsigned fenc(float f) {
    unsigned b = __float_as_uint(f);
    return (b & 0x80000000u) ? ~b : (b | 0x80000000u);
}

__device__ __forceinline__ float rawbf2f(unsigned short s) {
    return __uint_as_float(((unsigned)s) << 16);
}
__device__ __forceinline__ unsigned short f2rawbf(float f) {
    __hip_bfloat16 b = __float2bfloat16(f);
    unsigned short r; __builtin_memcpy(&r, &b, 2);
    return r;
}
__device__ __forceinline__ unsigned umin2(unsigned a, unsigned b) { return a < b ? a : b; }
__device__ __forceinline__ unsigned umax2(unsigned a, unsigned b) { return a > b ? a : b; }

// merged pre-pass: blocks 0..127 transpose W into MFMA-B bf16 hi/lo; blocks 128..131
// compute u vectors uvec[b][d] = sum_c W[d][h*128+c] * v[h][c], b = {s0,s1,d0,d1}
__global__ void k_pre(const float* __restrict__ W, const float* __restrict__ att_src,
                      const float* __restrict__ att_dst,
                      unsigned short* __restrict__ Wth, unsigned short* __restrict__ Wtl,
                      float* __restrict__ uvec) {
    __shared__ float vs[128];
    int b = blockIdx.x, t = threadIdx.x;
    if (b < 128) {
        int e = b * 256 + t;   // 32768
        int d = e >> 8, j = e & 255;
        int h = j >> 7, c = j & 127;
        int k = h * 128 + d;
        float w = W[e];
        unsigned short hi = f2rawbf(w);
        Wth[c * 256 + k] = hi;
        Wtl[c * 256 + k] = f2rawbf(w - rawbf2f(hi));
    } else {
        int bb = b - 128;
        int h = bb & 1;
        const float* v = (bb < 2 ? att_src : att_dst) + h * 128;
        if (t < 128) vs[t] = v[t];
        __syncthreads();
        int d = t >> 1, half = t & 1;
        const float* wr = W + (size_t)d * 256 + h * 128 + half * 64;
        float s = 0.f;
        for (int c = 0; c < 64; c++) s += wr[c] * vs[half * 64 + c];
        s += __shfl_xor(s, 1, 64);
        if (half == 0) uvec[bb * 128 + d] = s;
    }
}

// one wave per row: sq, xa=[-2x | hi(sq+512) lo | 0..], xb=[x | 1 1 | 0..],
// attention dots a_s/a_d via u-vectors, and zero-init of cnt/curs.
__global__ void k_conv(const float* __restrict__ x, const float* __restrict__ uvec,
                       float* __restrict__ sq,
                       unsigned short* __restrict__ xa, unsigned short* __restrict__ xb,
                       float* __restrict__ a_s, float* __restrict__ a_d,
                       int* __restrict__ cnt, int* __restrict__ curs) {
    int row = blockIdx.x * 4 + (threadIdx.x >> 6);
    int lane = threadIdx.x & 63;
    const float* xr = x + (size_t)row * GD;
    float a0 = xr[lane], a1 = xr[lane + 64];
    float s = wred(a0 * a0 + a1 * a1);
    unsigned short* ar = xa + (size_t)row * 144;
    unsigned short* br = xb + (size_t)row * 144;
    ar[lane] = f2rawbf(-2.f * a0); ar[lane + 64] = f2rawbf(-2.f * a1);
    br[lane] = f2rawbf(a0);        br[lane + 64] = f2rawbf(a1);
    float s0 = wred(a0 * uvec[lane]       + a1 * uvec[64 + lane]);
    float s1 = wred(a0 * uvec[128 + lane] + a1 * uvec[192 + lane]);
    float d0 = wred(a0 * uvec[256 + lane] + a1 * uvec[320 + lane]);
    float d1 = wred(a0 * uvec[384 + lane] + a1 * uvec[448 + lane]);
    if (lane < 16) {
        unsigned short av = 0, bv = 0;
        if (lane == 0)      { av = f2rawbf(s + 512.f); bv = 0x3F80; }
        else if (lane == 1) { float hi = rawbf2f(f2rawbf(s + 512.f));
                              av = f2rawbf(s + 512.f - hi); bv = 0x3F80; }
        ar[128 + lane] = av; br[128 + lane] = bv;
        if (lane == 0) {
            sq[row] = s;
            a_s[row * 2] = s0; a_s[row * 2 + 1] = s1;
            a_d[row * 2] = d0; a_d[row * 2 + 1] = d1;
            cnt[row] = 0; curs[row] = 0;
        }
    }
}

// MFMA candidate kNN. score'_ij = 512 + sq_i - 2 x_i.x_j (> 0 -> raw bits monotone).
// grid (64,16): 128 cols x 512-row superblock per block; top-4/superblock/col.
__launch_bounds__(256, 4)
__global__ void k_gemm_topk(const unsigned short* __restrict__ xa,
                            const unsigned short* __restrict__ xb,
                            unsigned* __restrict__ cand) {
    __shared__ unsigned short At[18 * 128 * 8];   // 36 KB, k-major 16B chunks
    int t = threadIdx.x;
    int w = t >> 6, lane = t & 63, h = lane >> 5, n = lane & 31;
    int col = blockIdx.x * 128 + w * 32 + n;
    int sb = blockIdx.y;   // 0..15

    short8 bfrag[9];
    #pragma unroll
    for (int kc = 0; kc < 9; kc++)
        bfrag[kc] = *(const short8*)(xb + (size_t)col * 144 + (2 * kc + h) * 8);

    unsigned T0 = 0xFFFFFFFFu, T1 = 0xFFFFFFFFu, T2 = 0xFFFFFFFFu, T3 = 0xFFFFFFFFu;

    for (int it = 0; it < 4; it++) {
        int rowbase = sb * 512 + it * 128;
        __syncthreads();
        #pragma unroll
        for (int s = 0; s < 9; s++) {
            int q = t + 256 * s;               // 0..2303
            int kb = q >> 7, r = q & 127;
            __builtin_amdgcn_global_load_lds(
                (const __attribute__((address_space(1))) unsigned*)
                    (xa + (size_t)(rowbase + r) * 144 + kb * 8),
                (__attribute__((address_space(3))) unsigned*)&At[q * 8],
                16, 0, 0);
        }
        __syncthreads();

        float16 acc[4];
        #pragma unroll
        for (int rs = 0; rs < 4; rs++) acc[rs] = (float16)(0.f);

        #pragma unroll
        for (int kc = 0; kc < 9; kc++) {
            short8 a[4];
            #pragma unroll
            for (int rs = 0; rs < 4; rs++)
                a[rs] = *(const short8*)&At[((2 * kc + h) * 128 + rs * 32 + n) * 8];
            #pragma unroll
            for (int rs = 0; rs < 4; rs++)
                acc[rs] = __builtin_amdgcn_mfma_f32_32x32x16_bf16(a[rs], bfrag[kc], acc[rs], 0, 0, 0);
        }

        #pragma unroll
        for (int rs = 0; rs < 4; rs++) {
            float16 A = acc[rs];
            unsigned b[16];
            #pragma unroll
            for (int r = 0; r < 16; r++) b[r] = __float_as_uint(A[r]);
            unsigned ma = umin2(umin2(umin2(b[0],b[1]),umin2(b[2],b[3])),
                                umin2(umin2(b[4],b[5]),umin2(b[6],b[7])));
            unsigned mb = umin2(umin2(umin2(b[8],b[9]),umin2(b[10],b[11])),
                                umin2(umin2(b[12],b[13]),umin2(b[14],b[15])));
            if ((umin2(ma, mb) & 0xFFFFE000u) <= T3) {
                int rb = rowbase + 4 * h + rs * 32;
                #pragma unroll
                for (int r = 0; r < 16; r++) {
                    unsigned k = (b[r] & 0xFFFFE000u) |
                                 (unsigned)(rb + (r & 3) + 8 * (r >> 2));
                    unsigned m0 = umax2(T0, k);  T0 = umin2(T0, k);
                    unsigned m1 = umax2(T1, m0); T1 = umin2(T1, m0);
                    unsigned m2 = umax2(T2, m1); T2 = umin2(T2, m1);
                    T3 = umin2(T3, m2);
                }
            }
        }
    }

    unsigned p0 = (unsigned)__shfl_xor((int)T0, 32), p1 = (unsigned)__shfl_xor((int)T1, 32),
             p2 = (unsigned)__shfl_xor((int)T2, 32), p3 = (unsigned)__shfl_xor((int)T3, 32);
    #pragma unroll
    for (int q = 0; q < 4; q++) {
        unsigned k = (q == 0) ? p0 : (q == 1) ? p1 : (q == 2) ? p2 : p3;
        unsigned m0 = umax2(T0, k);  T0 = umin2(T0, k);
        unsigned m1 = umax2(T1, m0); T1 = umin2(T1, m0);
        unsigned m2 = umax2(T2, m1); T2 = umin2(T2, m1);
        T3 = umin2(T3, m2);
    }

    if (h == 0) {
        uint4 o = make_uint4(T0, T1, T2, T3);
        *(uint4*)(cand + (size_t)col * 64 + sb * 4) = o;
    }
}

__device__ __forceinline__ int clampN(int v) {
    return v < 0 ? 0 : (v >= GN ? GN - 1 : v);
}

// two-stage refine. One wave per node.
// stage 1: top-16 of the 64 keys by (quantized noisy score | row) — coalesced 256 B,
//          16 select-and-remove min-butterflies (keys distinct: disjoint row ranges).
// stage 2: exact fp32 d2 for the 16 survivors; 4-lane group per candidate
//          (contiguous 128 B loads per group); top-3 lexicographic (d2, idx).
__global__ void k_refine(const unsigned* __restrict__ cand,
                         const float* __restrict__ x, const float* __restrict__ sq,
                         int* __restrict__ fidx, int* __restrict__ cnt) {
    int t = threadIdx.x, wv = t >> 6, lane = t & 63;
    int j = blockIdx.x * 4 + wv;
    int c = lane >> 2, g = lane & 3;

    unsigned key32 = cand[(size_t)j * 64 + lane];
    int myidx = 0;
    #pragma unroll
    for (int r = 0; r < 16; r++) {
        unsigned m = key32;
        #pragma unroll
        for (int o = 32; o > 0; o >>= 1)
            m = umin2(m, (unsigned)__shfl_xor((int)m, o, 64));
        myidx = (c == r) ? (int)(m & 8191u) : myidx;
        key32 = (key32 == m) ? 0xFFFFFFFFu : key32;
    }

    const float* xi = x + (size_t)myidx * GD + g * 32;
    const float* xj = x + (size_t)j * GD + g * 32;
    float p = 0.f;
    #pragma unroll
    for (int d4 = 0; d4 < 8; d4++) {
        float4 a = *(const float4*)(xi + d4 * 4);
        float4 b = *(const float4*)(xj + d4 * 4);
        p += a.x * b.x + a.y * b.y + a.z * b.z + a.w * b.w;
    }
    p += __shfl_xor(p, 1, 64);
    p += __shfl_xor(p, 2, 64);
    float d2 = sq[j] + sq[myidx] - 2.f * p;
    unsigned long long key = ((unsigned long long)fenc(d2) << 32) | (unsigned)myidx;

    int out3[3];
    #pragma unroll
    for (int r = 0; r < 3; r++) {
        unsigned long long k = key;
        #pragma unroll
        for (int o = 4; o <= 32; o <<= 1) {
            unsigned long long other = __shfl_xor(k, o, 64);
            k = k < other ? k : other;
        }
        out3[r] = (int)(unsigned)(k & 8191u);
        key = (key == k) ? ~0ull : key;   // group keys removed together (idx unique)
    }
    if (lane == 0) {
        int i0 = clampN(out3[0]), i1 = clampN(out3[1]), i2 = clampN(out3[2]);
        fidx[j * 3 + 0] = i0; fidx[j * 3 + 1] = i1; fidx[j * 3 + 2] = i2;
        atomicAdd(&cnt[i0], 1); atomicAdd(&cnt[i1], 1); atomicAdd(&cnt[i2], 1);
    }
}

__global__ void k_scan(const int* __restrict__ cnt, int* __restrict__ offs) {
    __shared__ int part[256];
    int t = threadIdx.x;
    int base = t * 32;
    int loc[32];
    int s = 0;
    #pragma unroll
    for (int k = 0; k < 32; k++) { loc[k] = s; s += cnt[base + k]; }
    part[t] = s;
    __syncthreads();
    if (t == 0) {
        int run = 0;
        for (int k = 0; k < 256; k++) { int v = part[k]; part[k] = run; run += v; }
        offs[GN] = run;
    }
    __syncthreads();
    int b = part[t];
    #pragma unroll
    for (int k = 0; k < 32; k++) offs[base + k] = b + loc[k];
}

// edge-parallel fill: CSR scatter + per-edge UNNORMALIZED softmax weights
__global__ void k_fill(const int* __restrict__ fidx, const int* __restrict__ offs,
                       int* __restrict__ cursor, int* __restrict__ elist,
                       const float* __restrict__ a_s, const float* __restrict__ a_d,
                       float2* __restrict__ ew) {
    int eid = blockIdx.x * 256 + threadIdx.x;
    int i = clampN(fidx[eid]);
    int src = eid / 3;
    float2 as = ((const float2*)a_s)[src];
    float2 ad = ((const float2*)a_d)[i];
    float e0 = as.x + ad.x; e0 = e0 >= 0.f ? e0 : NEG_SLOPE * e0;
    float e1 = as.y + ad.y; e1 = e1 >= 0.f ? e1 : NEG_SLOPE * e1;
    float w0 = expf(e0), w1 = expf(e1);
    int pos = atomicAdd(&cursor[i], 1);
    int slot = offs[i] + pos;
    if (slot < GN * GK) { elist[slot] = src; ew[slot] = make_float2(w0, w1); }
}

// fused aggregation: 16 nodes/block, 512 threads (8 waves; 2 nodes/wave).
__launch_bounds__(512, 4)
__global__ void k_out(const int* __restrict__ offs, const int* __restrict__ elst,
                      const float2* __restrict__ ew,
                      const float* __restrict__ x,
                      const unsigned short* __restrict__ Wth,
                      const unsigned short* __restrict__ Wtl,
                      const float* __restrict__ bias, const float* __restrict__ gamma,
                      const float* __restrict__ beta, float* __restrict__ out) {
    __shared__ unsigned short zh[16][264];
    __shared__ unsigned short zl[16][264];
    __shared__ float os[16][132];
    int t = threadIdx.x, i0 = blockIdx.x * 16;
    int wv = t >> 6, lane = t & 63;
    int eslot = lane >> 3, g = lane & 7;

    #pragma unroll
    for (int pp = 0; pp < 2; pp++) {
        int r = wv * 2 + pp, node = i0 + r;
        int s = offs[node], e = offs[node + 1];
        float acc0[16], acc1[16];
        #pragma unroll
        for (int q = 0; q < 16; q++) { acc0[q] = 0.f; acc1[q] = 0.f; }
        float w0s = 0.f, w1s = 0.f;
        for (int k0 = s; k0 < e; k0 += 8) {
            int k = k0 + eslot;
            bool valid = k < e;
            int j = valid ? elst[k] : 0;
            float2 wv2 = valid ? ew[k] : make_float2(0.f, 0.f);
            const float* xr = x + (size_t)j * GD + g * 16;
            float4 x0 = *(const float4*)(xr);
            float4 x1 = *(const float4*)(xr + 4);
            float4 x2 = *(const float4*)(xr + 8);
            float4 x3 = *(const float4*)(xr + 12);
            float xv[16] = {x0.x, x0.y, x0.z, x0.w, x1.x, x1.y, x1.z, x1.w,
                            x2.x, x2.y, x2.z, x2.w, x3.x, x3.y, x3.z, x3.w};
            #pragma unroll
            for (int q = 0; q < 16; q++) {
                acc0[q] += wv2.x * xv[q];
                acc1[q] += wv2.y * xv[q];
            }
            w0s += wv2.x; w1s += wv2.y;
        }
        #pragma unroll
        for (int m = 8; m <= 32; m <<= 1) {
            #pragma unroll
            for (int q = 0; q < 16; q++) {
                acc0[q] += __shfl_xor(acc0[q], m, 64);
                acc1[q] += __shfl_xor(acc1[q], m, 64);
            }
            w0s += __shfl_xor(w0s, m, 64);
            w1s += __shfl_xor(w1s, m, 64);
        }
        if (lane < 8) {
            float dn0 = 0.5f / w0s, dn1 = 0.5f / w1s;
            #pragma unroll
            for (int q = 0; q < 16; q += 2) {
                float a0 = acc0[q] * dn0, a1 = acc0[q + 1] * dn0;
                unsigned short h0 = f2rawbf(a0), h1 = f2rawbf(a1);
                *(unsigned*)&zh[r][lane * 16 + q] = (unsigned)h0 | ((unsigned)h1 << 16);
                *(unsigned*)&zl[r][lane * 16 + q] =
                    (unsigned)f2rawbf(a0 - rawbf2f(h0)) |
                    ((unsigned)f2rawbf(a1 - rawbf2f(h1)) << 16);
                float b0 = acc1[q] * dn1, b1 = acc1[q + 1] * dn1;
                unsigned short p0 = f2rawbf(b0), p1 = f2rawbf(b1);
                *(unsigned*)&zh[r][128 + lane * 16 + q] = (unsigned)p0 | ((unsigned)p1 << 16);
                *(unsigned*)&zl[r][128 + lane * 16 + q] =
                    (unsigned)f2rawbf(b0 - rawbf2f(p0)) |
                    ((unsigned)f2rawbf(b1 - rawbf2f(p1)) << 16);
            }
        }
    }
    __syncthreads();

    {
        int qd = lane >> 4, an = lane & 15;
        int c = wv * 16 + an;
        f32x4 acc = {0.f, 0.f, 0.f, 0.f};
        #pragma unroll
        for (int s = 0; s < 8; s++) {
            int ko = s * 32 + qd * 8;
            short8 ah = *(const short8*)&zh[an][ko];
            short8 al = *(const short8*)&zl[an][ko];
            short8 bh = *(const short8*)(Wth + (size_t)c * 256 + ko);
            short8 bl = *(const short8*)(Wtl + (size_t)c * 256 + ko);
            acc = __builtin_amdgcn_mfma_f32_16x16x32_bf16(ah, bh, acc, 0, 0, 0);
            acc = __builtin_amdgcn_mfma_f32_16x16x32_bf16(al, bh, acc, 0, 0, 0);
            acc = __builtin_amdgcn_mfma_f32_16x16x32_bf16(ah, bl, acc, 0, 0, 0);
        }
        #pragma unroll
        for (int r = 0; r < 4; r++) os[qd * 4 + r][c] = acc[r];
    }
    __syncthreads();

    #pragma unroll
    for (int pp = 0; pp < 2; pp++) {
        int r = wv * 2 + pp, node = i0 + r;
        float y0 = os[r][lane] + bias[lane];
        float y1 = os[r][lane + 64] + bias[lane + 64];
        float mu = wred(y0 + y1) * (1.f / 128.f);
        float c0 = y0 - mu, c1 = y1 - mu;
        float var = wred(c0 * c0 + c1 * c1) * (1.f / 128.f);
        float rs2 = 1.f / sqrtf(var + LN_EPS);
        float n0 = c0 * rs2 * gamma[lane] + beta[lane];
        float n1 = c1 * rs2 * gamma[lane + 64] + beta[lane + 64];
        n0 = n0 > 0.f ? n0 : 0.f;
        n1 = n1 > 0.f ? n1 : 0.f;
        out[(size_t)node * GD + lane]      = x[(size_t)node * GD + lane] + n0;
        out[(size_t)node * GD + lane + 64] = x[(size_t)node * GD + lane + 64] + n1;
    }
}

extern "C" void kernel_launch(void* const* d_in, const int* in_sizes, int n_in,
                              void* d_out, int out_size, void* d_ws, size_t ws_size,
                              hipStream_t stream) {
    const float* x       = (const float*)d_in[0];
    const float* W       = (const float*)d_in[2];
    const float* att_src = (const float*)d_in[3];
    const float* att_dst = (const float*)d_in[4];
    const float* bias    = (const float*)d_in[5];
    const float* gamma   = (const float*)d_in[6];
    const float* beta    = (const float*)d_in[7];
    float* out = (float*)d_out;

    char* w = (char*)d_ws;
    unsigned short* xa = (unsigned short*)w; w += (size_t)GN * 144 * 2;
    unsigned short* xb = (unsigned short*)w; w += (size_t)GN * 144 * 2;
    unsigned* cand = (unsigned*)w;           w += (size_t)GN * 64 * 4;
    float2* ew  = (float2*)w; w += (size_t)GN * GK * 8;
    unsigned short* Wth = (unsigned short*)w; w += (size_t)256 * 128 * 2;
    unsigned short* Wtl = (unsigned short*)w; w += (size_t)256 * 128 * 2;
    float* uvec = (float*)w; w += (size_t)4 * 128 * 4;
    float* sq   = (float*)w; w += (size_t)GN * 4;
    float* a_s  = (float*)w; w += (size_t)GN * GH * 4;
    float* a_d  = (float*)w; w += (size_t)GN * GH * 4;
    int*   fidx = (int*)w;   w += (size_t)GN * GK * 4;
    int*   cnt  = (int*)w;   w += (size_t)GN * 4;
    int*   curs = (int*)w;   w += (size_t)GN * 4;
    int*   offs = (int*)w;   w += (size_t)(GN + 1) * 4;
    int*   elst = (int*)w;   w += (size_t)GN * GK * 4;
    size_t need = (size_t)((char*)w - (char*)d_ws);
    if (ws_size < need) return;   // diagnostic guard

    k_pre<<<132, 256, 0, stream>>>(W, att_src, att_dst, Wth, Wtl, uvec);
    k_conv<<<GN / 4, 256, 0, stream>>>(x, uvec, sq, xa, xb, a_s, a_d, cnt, curs);
    k_gemm_topk<<<dim3(64, 16), 256, 0, stream>>>(xa, xb, cand);
    k_refine<<<GN / 4, 256, 0, stream>>>(cand, x, sq, fidx, cnt);
    k_scan<<<1, 256, 0, stream>>>(cnt, offs);
    k_fill<<<GN * GK / 256, 256, 0, stream>>>(fidx, offs, curs, elst, a_s, a_d, ew);
    k_out<<<GN / 16, 512, 0, stream>>>(offs, elst, ew, x, Wth, Wtl, bias, gamma, beta, out);
}